// Round 1
// baseline (609.594 us; speedup 1.0000x reference)
//
#include <hip/hip_runtime.h>
#include <math.h>

typedef __bf16 bf16;
typedef __attribute__((ext_vector_type(2))) __bf16 bf16x2;
typedef __attribute__((ext_vector_type(4))) __bf16 bf16x4;
typedef __attribute__((ext_vector_type(8))) __bf16 bf16x8;
typedef __attribute__((ext_vector_type(4))) float f32x4;

#define GLD16(g, l) __builtin_amdgcn_global_load_lds( \
    (const __attribute__((address_space(1))) void*)(g), \
    (__attribute__((address_space(3))) void*)(l), 16, 0, 0)

// ---------------- elementwise helpers ----------------

__global__ void cast_bf16_kernel(const float* __restrict__ in, bf16* __restrict__ out, int n4) {
  int i = blockIdx.x * blockDim.x + threadIdx.x;
  if (i >= n4) return;
  float4 f = ((const float4*)in)[i];
  bf16x4 o;
  o[0] = (bf16)f.x; o[1] = (bf16)f.y; o[2] = (bf16)f.z; o[3] = (bf16)f.w;
  ((bf16x4*)out)[i] = o;
}

__global__ void bias_cat_kernel(const float* __restrict__ bq, const float* __restrict__ bk,
                                const float* __restrict__ bv, float* __restrict__ out) {
  int i = blockIdx.x * blockDim.x + threadIdx.x;
  if (i >= 6144) return;
  out[i] = (i < 2048) ? bq[i] : (i < 4096 ? bk[i - 2048] : bv[i - 4096]);
}

__global__ void rope_table_kernel(float* __restrict__ cost, float* __restrict__ sint) {
  int i = blockIdx.x * blockDim.x + threadIdx.x;  // S*64 threads
  int s = i >> 6, d = i & 63;
  float inv = powf(10000.0f, -(float)d / 64.0f);
  float ang = (float)s * inv;
  cost[i] = cosf(ang);
  sint[i] = sinf(ang);
}

// qkv: (B*S, 6144) bf16 -> q_r/k_r/v_r: (B*H, S, 128) bf16 with RoPE on q,k
__global__ void rope_transpose_kernel(const bf16* __restrict__ qkv,
                                      const float* __restrict__ cost, const float* __restrict__ sint,
                                      bf16* __restrict__ qr, bf16* __restrict__ kr, bf16* __restrict__ vr) {
  int idx = blockIdx.x * blockDim.x + threadIdx.x;  // B*S*H*D = 2^23 threads
  int d = idx & 127;
  int h = (idx >> 7) & 15;
  int s = (idx >> 11) & 2047;
  int b = idx >> 22;
  const bf16* row = qkv + (size_t)(b * 2048 + s) * 6144;
  float c  = cost[(s << 6) | (d & 63)];
  float sn = sint[(s << 6) | (d & 63)];
  float qv = (float)row[(h << 7) | d];
  float qp = (float)row[(h << 7) | (d ^ 64)];
  float kv = (float)row[2048 + ((h << 7) | d)];
  float kp = (float)row[2048 + ((h << 7) | (d ^ 64))];
  float vv = (float)row[4096 + ((h << 7) | d)];
  float qrot = (d < 64) ? -qp : qp;   // rotate_half
  float krot = (d < 64) ? -kp : kp;
  size_t o = ((size_t)((b << 4) | h) * 2048 + s) * 128 + d;
  qr[o] = (bf16)(qv * c + qrot * sn);
  kr[o] = (bf16)(kv * c + krot * sn);
  vr[o] = (bf16)vv;
}

// ---------------- GEMM: C = A @ B^T + bias (A: MxK, B: NxK, both bf16 row-major) ----------------
// m97 structure: 128x128 tile, 4 waves 2x2, 16x16x32 bf16 MFMA, global_load_lds(16B), 2 barriers/K-step.
template<bool OUT_BF16>
__global__ __launch_bounds__(256)
void gemm_bt_kernel(const bf16* __restrict__ A, const bf16* __restrict__ B,
                    const float* __restrict__ bias, void* __restrict__ Cp,
                    int M, int N, int K) {
  __shared__ bf16 Al[128 * 32];
  __shared__ bf16 Bl[128 * 32];
  const int t = threadIdx.x;
  const int wid = t >> 6, lane = t & 63;
  const int wr = wid >> 1, wc = wid & 1;
  const int lr = lane & 15, lk = lane >> 4;
  const int tm = blockIdx.y, tn = blockIdx.x;
  const bf16* Ab = A + (size_t)tm * 128 * K;
  const bf16* Bb = B + (size_t)tn * 128 * K;
  f32x4 acc[4][4] = {};
  for (int k0 = 0; k0 < K; k0 += 32) {
    __syncthreads();  // previous tile's reads complete before overwrite
#pragma unroll
    for (int c = 0; c < 2; ++c) {
      int e = (c * 256 + t) * 8;       // flat bf16 element index in tile
      int row = e >> 5, kk = e & 31;   // [128][32] row-major
      GLD16(Ab + (size_t)row * K + k0 + kk, &Al[e]);
      GLD16(Bb + (size_t)row * K + k0 + kk, &Bl[e]);
    }
    __syncthreads();  // drains vmcnt -> LDS tiles valid
    bf16x8 af[4], bf[4];
#pragma unroll
    for (int m = 0; m < 4; ++m) af[m] = *(const bf16x8*)&Al[(wr * 64 + m * 16 + lr) * 32 + lk * 8];
#pragma unroll
    for (int n = 0; n < 4; ++n) bf[n] = *(const bf16x8*)&Bl[(wc * 64 + n * 16 + lr) * 32 + lk * 8];
#pragma unroll
    for (int m = 0; m < 4; ++m)
#pragma unroll
      for (int n = 0; n < 4; ++n)
        acc[m][n] = __builtin_amdgcn_mfma_f32_16x16x32_bf16(af[m], bf[n], acc[m][n], 0, 0, 0);
  }
  const int rb = tm * 128 + wr * 64, cb = tn * 128 + wc * 64;
#pragma unroll
  for (int n = 0; n < 4; ++n) {
    int col = cb + n * 16 + lr;      // C/D: col = lane&15
    float bvl = bias[col];
#pragma unroll
    for (int m = 0; m < 4; ++m) {
#pragma unroll
      for (int r = 0; r < 4; ++r) {
        int row = rb + m * 16 + lk * 4 + r;  // C/D: row = (lane>>4)*4 + reg
        float v = acc[m][n][r] + bvl;
        if (OUT_BF16) ((bf16*)Cp)[(size_t)row * N + col] = (bf16)v;
        else          ((float*)Cp)[(size_t)row * N + col] = v;
      }
    }
  }
}

// ---------------- causal flash attention ----------------
// Q,K,V: (B*H, S, 128) bf16. O: (B, S, H*128) bf16. 64 q-rows/block, 4 waves x 16 rows, KVBLK=64.
__global__ __launch_bounds__(256)
void attn_kernel(const bf16* __restrict__ Q, const bf16* __restrict__ Kc,
                 const bf16* __restrict__ V, bf16* __restrict__ O, int S) {
  __shared__ bf16 Kl[64 * 128];     // [kv][d], 16B chunks XOR-swizzled by kv&7 (pre-swizzled source)
  __shared__ bf16 Vt[128 * 64];     // [d][kv], 16B chunks XOR-swizzled by d&7
  __shared__ bf16 Pl[4][16 * 64];   // per-wave P, rows XOR-swizzled by row&7
  const int t = threadIdx.x, wid = t >> 6, lane = t & 63;
  const int lr = lane & 15, lk = lane >> 4;
  const int bh = blockIdx.y;
  const int qt = (int)gridDim.x - 1 - (int)blockIdx.x;  // heavy blocks dispatched first
  const int q0 = qt * 64;
  const bf16* Qb = Q + (size_t)bh * S * 128;
  const bf16* Kb = Kc + (size_t)bh * S * 128;
  const bf16* Vb = V + (size_t)bh * S * 128;
  bf16x8 qf[4];
  const int qrow = q0 + wid * 16 + lr;
#pragma unroll
  for (int kb = 0; kb < 4; ++kb)
    qf[kb] = *(const bf16x8*)&Qb[(size_t)qrow * 128 + kb * 32 + lk * 8];
  f32x4 o[8] = {};
  float mrun[4], lrun[4];
#pragma unroll
  for (int r = 0; r < 4; ++r) { mrun[r] = -INFINITY; lrun[r] = 0.f; }
  const float scale = 0.08838834764831845f;  // 1/sqrt(128)
  const int ntiles = qt + 1;
  for (int tt = 0; tt < ntiles; ++tt) {
    const int kv0 = tt * 64;
    __syncthreads();  // previous tile's LDS reads complete
    // stage K: LDS chunk (kv, cc) <- global chunk cc ^ (kv&7)  (rule 21: swizzle source, linear dest)
#pragma unroll
    for (int c = 0; c < 4; ++c) {
      int fc = c * 256 + t;
      int kvr = fc >> 4, cc = fc & 15;
      int src = (cc ^ (kvr & 7)) * 8;
      GLD16(Kb + (size_t)(kv0 + kvr) * 128 + src, &Kl[fc * 8]);
    }
    // stage V transposed, b32 writes of kv-pairs, chunk-swizzled by d&7 (conflict-free both sides)
    {
      int p2 = t & 31;   // kv pair index
      int w8 = t >> 5;   // 0..7
      int kv = p2 * 2;
#pragma unroll
      for (int i = 0; i < 2; ++i) {
        int d0 = (w8 + i * 8) * 8;
        bf16x8 v0 = *(const bf16x8*)&Vb[(size_t)(kv0 + kv) * 128 + d0];
        bf16x8 v1 = *(const bf16x8*)&Vb[(size_t)(kv0 + kv + 1) * 128 + d0];
#pragma unroll
        for (int j = 0; j < 8; ++j) {
          int d = d0 + j;
          int e = (d * 64 + kv) ^ ((d & 7) << 3);
          bf16x2 pr; pr[0] = v0[j]; pr[1] = v1[j];
          *(bf16x2*)&Vt[e] = pr;
        }
      }
    }
    __syncthreads();
    // S = Q K^T  (16x64 per wave)
    f32x4 sa[4];
#pragma unroll
    for (int n = 0; n < 4; ++n) {
      sa[n] = (f32x4){0.f, 0.f, 0.f, 0.f};
      int kvl = n * 16 + lr;  // B-operand col
#pragma unroll
      for (int kb = 0; kb < 4; ++kb) {
        bf16x8 kf = *(const bf16x8*)&Kl[kvl * 128 + (((kb << 2) | lk) ^ (kvl & 7)) * 8];
        sa[n] = __builtin_amdgcn_mfma_f32_16x16x32_bf16(qf[kb], kf, sa[n], 0, 0, 0);
      }
    }
    // online softmax
    float p[4][4];
    float tmax[4] = {-INFINITY, -INFINITY, -INFINITY, -INFINITY};
    const bool lastTile = (tt == ntiles - 1);
#pragma unroll
    for (int n = 0; n < 4; ++n)
#pragma unroll
      for (int r = 0; r < 4; ++r) {
        float s = sa[n][r] * scale;
        if (lastTile) {  // only the diagonal tile needs masking
          int kvg = kv0 + n * 16 + lr;
          int qg = q0 + wid * 16 + lk * 4 + r;
          if (kvg > qg) s = -INFINITY;
        }
        p[n][r] = s;
        tmax[r] = fmaxf(tmax[r], s);
      }
#pragma unroll
    for (int r = 0; r < 4; ++r)
#pragma unroll
      for (int off = 1; off < 16; off <<= 1)
        tmax[r] = fmaxf(tmax[r], __shfl_xor(tmax[r], off));
    float alpha[4], rsum[4];
#pragma unroll
    for (int r = 0; r < 4; ++r) {
      float mnew = fmaxf(mrun[r], tmax[r]);
      alpha[r] = __expf(mrun[r] - mnew);
      mrun[r] = mnew;
      rsum[r] = 0.f;
#pragma unroll
      for (int n = 0; n < 4; ++n) {
        p[n][r] = __expf(p[n][r] - mnew);
        rsum[r] += p[n][r];
      }
    }
#pragma unroll
    for (int r = 0; r < 4; ++r) {
#pragma unroll
      for (int off = 1; off < 16; off <<= 1)
        rsum[r] += __shfl_xor(rsum[r], off);
      lrun[r] = lrun[r] * alpha[r] + rsum[r];
    }
#pragma unroll
    for (int n8 = 0; n8 < 8; ++n8)
#pragma unroll
      for (int r = 0; r < 4; ++r)
        o[n8][r] *= alpha[r];
    // write P (bf16) to per-wave LDS, row-swizzled
#pragma unroll
    for (int n = 0; n < 4; ++n)
#pragma unroll
      for (int r = 0; r < 4; ++r) {
        int row = lk * 4 + r, col = n * 16 + lr;
        Pl[wid][(row * 64 + col) ^ ((row & 7) << 3)] = (bf16)p[n][r];
      }
    __syncthreads();  // P visible (and all waves aligned before next restage)
    // O += P @ V
#pragma unroll
    for (int kb2 = 0; kb2 < 2; ++kb2) {
      bf16x8 pf = *(const bf16x8*)&Pl[wid][(lr * 64 + kb2 * 32 + lk * 8) ^ ((lr & 7) << 3)];
#pragma unroll
      for (int n8 = 0; n8 < 8; ++n8) {
        int dcol = n8 * 16 + lr;
        bf16x8 vf = *(const bf16x8*)&Vt[(dcol * 64 + kb2 * 32 + lk * 8) ^ ((dcol & 7) << 3)];
        o[n8] = __builtin_amdgcn_mfma_f32_16x16x32_bf16(pf, vf, o[n8], 0, 0, 0);
      }
    }
  }
  // epilogue: normalize and store to (B, S, H*128)
  const int b = bh >> 4, h = bh & 15;
#pragma unroll
  for (int r = 0; r < 4; ++r) {
    float rl = 1.0f / lrun[r];
    int row = q0 + wid * 16 + lk * 4 + r;
    size_t base = ((size_t)(b * 2048 + row)) * 2048 + h * 128;
#pragma unroll
    for (int n8 = 0; n8 < 8; ++n8)
      O[base + n8 * 16 + lr] = (bf16)(o[n8][r] * rl);
  }
}

// ---------------- launch ----------------

extern "C" void kernel_launch(void* const* d_in, const int* in_sizes, int n_in,
                              void* d_out, int out_size, void* d_ws, size_t ws_size,
                              hipStream_t stream) {
  const float* x  = (const float*)d_in[0];
  const float* Wq = (const float*)d_in[1];
  const float* bq = (const float*)d_in[2];
  const float* Wk = (const float*)d_in[3];
  const float* bk = (const float*)d_in[4];
  const float* Wv = (const float*)d_in[5];
  const float* bv = (const float*)d_in[6];
  const float* Wo = (const float*)d_in[7];
  const float* bo = (const float*)d_in[8];

  char* ws = (char*)d_ws;
  bf16* xb     = (bf16*)(ws);                  // 16 MB (x bf16; reused as q_rope after GEMM1)
  bf16* wqkv   = (bf16*)(ws + 16777216);       // 24 MB (Wq|Wk|Wv bf16, 6144x2048)
  bf16* wob    = (bf16*)(ws + 41943040);       // 8 MB
  bf16* qkv    = (bf16*)(ws + 50331648);       // 48 MB (first 16 MB reused as attn_out)
  bf16* kr     = (bf16*)(ws + 100663296);      // 16 MB
  bf16* vr     = (bf16*)(ws + 117440512);      // 16 MB
  float* biasq = (float*)(ws + 134217728);     // 24 KB
  float* cost  = (float*)(ws + 134242304);     // 512 KB
  float* sint  = (float*)(ws + 134766592);     // 512 KB (ws end: 135290880)
  bf16* qr = xb;          // alias: x_bf16 is dead after GEMM1
  bf16* attn_out = qkv;   // alias: qkv is dead after rope_transpose

  cast_bf16_kernel<<<8192, 256, 0, stream>>>(x, xb, 2097152);
  cast_bf16_kernel<<<4096, 256, 0, stream>>>(Wq, wqkv, 1048576);
  cast_bf16_kernel<<<4096, 256, 0, stream>>>(Wk, wqkv + 2048 * 2048, 1048576);
  cast_bf16_kernel<<<4096, 256, 0, stream>>>(Wv, wqkv + 2 * 2048 * 2048, 1048576);
  cast_bf16_kernel<<<4096, 256, 0, stream>>>(Wo, wob, 1048576);
  bias_cat_kernel<<<24, 256, 0, stream>>>(bq, bk, bv, biasq);
  rope_table_kernel<<<512, 256, 0, stream>>>(cost, sint);
  // qkv = x @ [Wq|Wk|Wv]^T + bias  (4096 x 6144 x 2048)
  gemm_bt_kernel<true><<<dim3(48, 32), 256, 0, stream>>>(xb, wqkv, biasq, qkv, 4096, 6144, 2048);
  rope_transpose_kernel<<<32768, 256, 0, stream>>>(qkv, cost, sint, qr, kr, vr);
  attn_kernel<<<dim3(32, 32), 256, 0, stream>>>(qr, kr, vr, attn_out, 2048);
  // out = attn @ Wo^T + bo  (4096 x 2048 x 2048), fp32 out
  gemm_bt_kernel<false><<<dim3(16, 32), 256, 0, stream>>>(attn_out, wob, bo, (float*)d_out, 4096, 2048, 2048);
}

// Round 2
// 534.370 us; speedup vs baseline: 1.1408x; 1.1408x over previous
//
#include <hip/hip_runtime.h>
#include <math.h>

typedef __bf16 bf16;
typedef __attribute__((ext_vector_type(2))) __bf16 bf16x2;
typedef __attribute__((ext_vector_type(4))) __bf16 bf16x4;
typedef __attribute__((ext_vector_type(8))) __bf16 bf16x8;
typedef __attribute__((ext_vector_type(4))) float f32x4;

#define GLD16(g, l) __builtin_amdgcn_global_load_lds( \
    (const __attribute__((address_space(1))) void*)(g), \
    (__attribute__((address_space(3))) void*)(l), 16, 0, 0)

// ---------------- elementwise helpers ----------------

__global__ void cast_bf16_kernel(const float* __restrict__ in, bf16* __restrict__ out, int n4) {
  int i = blockIdx.x * blockDim.x + threadIdx.x;
  if (i >= n4) return;
  float4 f = ((const float4*)in)[i];
  bf16x4 o;
  o[0] = (bf16)f.x; o[1] = (bf16)f.y; o[2] = (bf16)f.z; o[3] = (bf16)f.w;
  ((bf16x4*)out)[i] = o;
}

__global__ void bias_cat_kernel(const float* __restrict__ bq, const float* __restrict__ bk,
                                const float* __restrict__ bv, float* __restrict__ out) {
  int i = blockIdx.x * blockDim.x + threadIdx.x;
  if (i >= 6144) return;
  out[i] = (i < 2048) ? bq[i] : (i < 4096 ? bk[i - 2048] : bv[i - 4096]);
}

__global__ void rope_table_kernel(float* __restrict__ cost, float* __restrict__ sint) {
  int i = blockIdx.x * blockDim.x + threadIdx.x;  // S*64 threads
  int s = i >> 6, d = i & 63;
  float inv = powf(10000.0f, -(float)d / 64.0f);
  float ang = (float)s * inv;
  cost[i] = cosf(ang);
  sint[i] = sinf(ang);
}

// qkv: (B*S, 6144) bf16 -> q_r/k_r/v_r: (B*H, S, 128) bf16 with RoPE on q,k
__global__ void rope_transpose_kernel(const bf16* __restrict__ qkv,
                                      const float* __restrict__ cost, const float* __restrict__ sint,
                                      bf16* __restrict__ qr, bf16* __restrict__ kr, bf16* __restrict__ vr) {
  int idx = blockIdx.x * blockDim.x + threadIdx.x;  // B*S*H*D = 2^23 threads
  int d = idx & 127;
  int h = (idx >> 7) & 15;
  int s = (idx >> 11) & 2047;
  int b = idx >> 22;
  const bf16* row = qkv + (size_t)(b * 2048 + s) * 6144;
  float c  = cost[(s << 6) | (d & 63)];
  float sn = sint[(s << 6) | (d & 63)];
  float qv = (float)row[(h << 7) | d];
  float qp = (float)row[(h << 7) | (d ^ 64)];
  float kv = (float)row[2048 + ((h << 7) | d)];
  float kp = (float)row[2048 + ((h << 7) | (d ^ 64))];
  float vv = (float)row[4096 + ((h << 7) | d)];
  float qrot = (d < 64) ? -qp : qp;   // rotate_half
  float krot = (d < 64) ? -kp : kp;
  size_t o = ((size_t)((b << 4) | h) * 2048 + s) * 128 + d;
  qr[o] = (bf16)(qv * c + qrot * sn);
  kr[o] = (bf16)(kv * c + krot * sn);
  vr[o] = (bf16)vv;
}

// vr: (32 bh, 2048 s, 128 d) -> vt: (32 bh, 128 d, 2048 s). LDS-tiled, both sides coalesced.
__global__ void transpose_v_kernel(const bf16* __restrict__ vr, bf16* __restrict__ vt) {
  __shared__ bf16 Vl[64 * 72];  // 64 s-rows x 64 d-cols, stride 72 breaks conflicts
  const int bh = blockIdx.z;    // 32
  const int st = blockIdx.y;    // 32
  const int dt = blockIdx.x;    // 2
  const bf16* src = vr + ((size_t)bh * 2048 + st * 64) * 128 + dt * 64;
  bf16* dst = vt + ((size_t)bh * 128 + dt * 64) * 2048 + st * 64;
  const int t = threadIdx.x;
#pragma unroll
  for (int i = 0; i < 2; ++i) {
    int c = i * 256 + t;                 // 512 chunks of 8
    int r = c >> 3, c0 = (c & 7) * 8;    // r = s index, c0 = d index
    *(bf16x8*)&Vl[r * 72 + c0] = *(const bf16x8*)&src[(size_t)r * 128 + c0];
  }
  __syncthreads();
#pragma unroll
  for (int i = 0; i < 2; ++i) {
    int c = i * 256 + t;
    int r = c >> 3, c0 = (c & 7) * 8;    // r = d index, c0 = s index
    bf16x8 v;
#pragma unroll
    for (int j = 0; j < 8; ++j) v[j] = Vl[(c0 + j) * 72 + r];
    *(bf16x8*)&dst[(size_t)r * 2048 + c0] = v;
  }
}

// ---------------- GEMM: C = A @ B^T + bias (A: MxK, B: NxK, both bf16 row-major) ----------------
// m97 structure: 128x128 tile, 4 waves 2x2, 16x16x32 bf16 MFMA, global_load_lds(16B), 2 barriers/K-step.
template<bool OUT_BF16>
__global__ __launch_bounds__(256)
void gemm_bt_kernel(const bf16* __restrict__ A, const bf16* __restrict__ B,
                    const float* __restrict__ bias, void* __restrict__ Cp,
                    int M, int N, int K) {
  __shared__ bf16 Al[128 * 32];
  __shared__ bf16 Bl[128 * 32];
  const int t = threadIdx.x;
  const int wid = t >> 6, lane = t & 63;
  const int wr = wid >> 1, wc = wid & 1;
  const int lr = lane & 15, lk = lane >> 4;
  const int tm = blockIdx.y, tn = blockIdx.x;
  const bf16* Ab = A + (size_t)tm * 128 * K;
  const bf16* Bb = B + (size_t)tn * 128 * K;
  f32x4 acc[4][4] = {};
  for (int k0 = 0; k0 < K; k0 += 32) {
    __syncthreads();  // previous tile's reads complete before overwrite
#pragma unroll
    for (int c = 0; c < 2; ++c) {
      int e = (c * 256 + t) * 8;       // flat bf16 element index in tile
      int row = e >> 5, kk = e & 31;   // [128][32] row-major
      GLD16(Ab + (size_t)row * K + k0 + kk, &Al[e]);
      GLD16(Bb + (size_t)row * K + k0 + kk, &Bl[e]);
    }
    __syncthreads();  // drains vmcnt -> LDS tiles valid
    bf16x8 af[4], bf[4];
#pragma unroll
    for (int m = 0; m < 4; ++m) af[m] = *(const bf16x8*)&Al[(wr * 64 + m * 16 + lr) * 32 + lk * 8];
#pragma unroll
    for (int n = 0; n < 4; ++n) bf[n] = *(const bf16x8*)&Bl[(wc * 64 + n * 16 + lr) * 32 + lk * 8];
#pragma unroll
    for (int m = 0; m < 4; ++m)
#pragma unroll
      for (int n = 0; n < 4; ++n)
        acc[m][n] = __builtin_amdgcn_mfma_f32_16x16x32_bf16(af[m], bf[n], acc[m][n], 0, 0, 0);
  }
  const int rb = tm * 128 + wr * 64, cb = tn * 128 + wc * 64;
#pragma unroll
  for (int n = 0; n < 4; ++n) {
    int col = cb + n * 16 + lr;      // C/D: col = lane&15
    float bvl = bias[col];
#pragma unroll
    for (int m = 0; m < 4; ++m) {
#pragma unroll
      for (int r = 0; r < 4; ++r) {
        int row = rb + m * 16 + lk * 4 + r;  // C/D: row = (lane>>4)*4 + reg
        float v = acc[m][n][r] + bvl;
        if (OUT_BF16) ((bf16*)Cp)[(size_t)row * N + col] = (bf16)v;
        else          ((float*)Cp)[(size_t)row * N + col] = v;
      }
    }
  }
}

// ---------------- causal flash attention ----------------
// Q,K: (B*H, S, 128) bf16; Vt: (B*H, 128, S) bf16 (pre-transposed). O: (B, S, H*128) bf16.
// 64 q-rows/block, 4 waves x 16 rows, KVBLK=64. All staging via coalesced global_load_lds.
__global__ __launch_bounds__(256)
void attn_kernel(const bf16* __restrict__ Q, const bf16* __restrict__ Kc,
                 const bf16* __restrict__ Vtg, bf16* __restrict__ O, int S) {
  __shared__ bf16 Kl[64 * 128];     // [kv][d], 16B chunks XOR-swizzled by kv&7 (pre-swizzled source)
  __shared__ bf16 Vt[128 * 64];     // [d][kv], 16B chunks XOR-swizzled by d&7 (pre-swizzled source)
  __shared__ bf16 Pl[4][16 * 64];   // per-wave P, rows XOR-swizzled by row&7
  const int t = threadIdx.x, wid = t >> 6, lane = t & 63;
  const int lr = lane & 15, lk = lane >> 4;
  const int bh = blockIdx.y;
  const int qt = (int)gridDim.x - 1 - (int)blockIdx.x;  // heavy blocks dispatched first
  const int q0 = qt * 64;
  const bf16* Qb = Q + (size_t)bh * S * 128;
  const bf16* Kb = Kc + (size_t)bh * S * 128;
  const bf16* Vb = Vtg + (size_t)bh * 128 * S;
  bf16x8 qf[4];
  const int qrow = q0 + wid * 16 + lr;
#pragma unroll
  for (int kb = 0; kb < 4; ++kb)
    qf[kb] = *(const bf16x8*)&Qb[(size_t)qrow * 128 + kb * 32 + lk * 8];
  f32x4 o[8] = {};
  float mrun[4], lrun[4];
#pragma unroll
  for (int r = 0; r < 4; ++r) { mrun[r] = -INFINITY; lrun[r] = 0.f; }
  const float scale = 0.08838834764831845f;  // 1/sqrt(128)
  const int ntiles = qt + 1;
  for (int tt = 0; tt < ntiles; ++tt) {
    const int kv0 = tt * 64;
    __syncthreads();  // previous tile's LDS reads complete before restage
    // stage K tile [64][128] and V^T tile [128][64]; linear LDS dest, swizzled global source (rule 21)
#pragma unroll
    for (int c = 0; c < 4; ++c) {
      int fc = c * 256 + t;
      int kvr = fc >> 4, cc = fc & 15;
      GLD16(Kb + (size_t)(kv0 + kvr) * 128 + (cc ^ (kvr & 7)) * 8, &Kl[fc * 8]);
      int dr = fc >> 3, c2 = fc & 7;
      GLD16(Vb + (size_t)dr * S + kv0 + (c2 ^ (dr & 7)) * 8, &Vt[fc * 8]);
    }
    __syncthreads();  // drains vmcnt -> tiles valid
    // S = Q K^T  (16x64 per wave)
    f32x4 sa[4];
#pragma unroll
    for (int n = 0; n < 4; ++n) {
      sa[n] = (f32x4){0.f, 0.f, 0.f, 0.f};
      int kvl = n * 16 + lr;  // B-operand col
#pragma unroll
      for (int kb = 0; kb < 4; ++kb) {
        bf16x8 kf = *(const bf16x8*)&Kl[kvl * 128 + (((kb << 2) | lk) ^ (kvl & 7)) * 8];
        sa[n] = __builtin_amdgcn_mfma_f32_16x16x32_bf16(qf[kb], kf, sa[n], 0, 0, 0);
      }
    }
    // online softmax
    float p[4][4];
    float tmax[4] = {-INFINITY, -INFINITY, -INFINITY, -INFINITY};
    const bool lastTile = (tt == ntiles - 1);
#pragma unroll
    for (int n = 0; n < 4; ++n)
#pragma unroll
      for (int r = 0; r < 4; ++r) {
        float s = sa[n][r] * scale;
        if (lastTile) {  // only the diagonal tile needs masking
          int kvg = kv0 + n * 16 + lr;
          int qg = q0 + wid * 16 + lk * 4 + r;
          if (kvg > qg) s = -INFINITY;
        }
        p[n][r] = s;
        tmax[r] = fmaxf(tmax[r], s);
      }
#pragma unroll
    for (int r = 0; r < 4; ++r)
#pragma unroll
      for (int off = 1; off < 16; off <<= 1)
        tmax[r] = fmaxf(tmax[r], __shfl_xor(tmax[r], off));
    float alpha[4], rsum[4];
#pragma unroll
    for (int r = 0; r < 4; ++r) {
      float mnew = fmaxf(mrun[r], tmax[r]);
      alpha[r] = __expf(mrun[r] - mnew);
      mrun[r] = mnew;
      rsum[r] = 0.f;
#pragma unroll
      for (int n = 0; n < 4; ++n) {
        p[n][r] = __expf(p[n][r] - mnew);
        rsum[r] += p[n][r];
      }
    }
#pragma unroll
    for (int r = 0; r < 4; ++r) {
#pragma unroll
      for (int off = 1; off < 16; off <<= 1)
        rsum[r] += __shfl_xor(rsum[r], off);
      lrun[r] = lrun[r] * alpha[r] + rsum[r];
    }
#pragma unroll
    for (int n8 = 0; n8 < 8; ++n8)
#pragma unroll
      for (int r = 0; r < 4; ++r)
        o[n8][r] *= alpha[r];
    // write P (bf16) to per-wave LDS, row-swizzled; same-wave write->read needs only lgkmcnt
#pragma unroll
    for (int n = 0; n < 4; ++n)
#pragma unroll
      for (int r = 0; r < 4; ++r) {
        int row = lk * 4 + r, col = n * 16 + lr;
        Pl[wid][(row * 64 + col) ^ ((row & 7) << 3)] = (bf16)p[n][r];
      }
    // O += P @ V
#pragma unroll
    for (int kb2 = 0; kb2 < 2; ++kb2) {
      bf16x8 pf = *(const bf16x8*)&Pl[wid][(lr * 64 + kb2 * 32 + lk * 8) ^ ((lr & 7) << 3)];
#pragma unroll
      for (int n8 = 0; n8 < 8; ++n8) {
        int dcol = n8 * 16 + lr;
        bf16x8 vf = *(const bf16x8*)&Vt[(dcol * 64 + kb2 * 32 + lk * 8) ^ ((dcol & 7) << 3)];
        o[n8] = __builtin_amdgcn_mfma_f32_16x16x32_bf16(pf, vf, o[n8], 0, 0, 0);
      }
    }
  }
  // epilogue: normalize and store to (B, S, H*128)
  const int b = bh >> 4, h = bh & 15;
#pragma unroll
  for (int r = 0; r < 4; ++r) {
    float rl = 1.0f / lrun[r];
    int row = q0 + wid * 16 + lk * 4 + r;
    size_t base = ((size_t)(b * 2048 + row)) * 2048 + h * 128;
#pragma unroll
    for (int n8 = 0; n8 < 8; ++n8)
      O[base + n8 * 16 + lr] = (bf16)(o[n8][r] * rl);
  }
}

// ---------------- launch ----------------

extern "C" void kernel_launch(void* const* d_in, const int* in_sizes, int n_in,
                              void* d_out, int out_size, void* d_ws, size_t ws_size,
                              hipStream_t stream) {
  const float* x  = (const float*)d_in[0];
  const float* Wq = (const float*)d_in[1];
  const float* bq = (const float*)d_in[2];
  const float* Wk = (const float*)d_in[3];
  const float* bk = (const float*)d_in[4];
  const float* Wv = (const float*)d_in[5];
  const float* bv = (const float*)d_in[6];
  const float* Wo = (const float*)d_in[7];
  const float* bo = (const float*)d_in[8];

  char* ws = (char*)d_ws;
  bf16* xb     = (bf16*)(ws);                  // 16 MB (x bf16; reused as q_rope after GEMM1)
  bf16* wqkv   = (bf16*)(ws + 16777216);       // 24 MB (Wq|Wk|Wv bf16, 6144x2048)
  bf16* wob    = (bf16*)(ws + 41943040);       // 8 MB
  bf16* qkv    = (bf16*)(ws + 50331648);       // 48 MB; [0,16MB) reused as attn_out, [16,32MB) as V^T
  bf16* kr     = (bf16*)(ws + 100663296);      // 16 MB
  bf16* vr     = (bf16*)(ws + 117440512);      // 16 MB (row-major V, transposed -> vt)
  float* biasq = (float*)(ws + 134217728);     // 24 KB
  float* cost  = (float*)(ws + 134242304);     // 512 KB
  float* sint  = (float*)(ws + 134766592);     // 512 KB (ws end: 135290880)
  bf16* qr = xb;                               // alias: x_bf16 dead after GEMM1
  bf16* attn_out = qkv;                        // alias: qkv[0,16MB) dead after rope_transpose
  bf16* vt = (bf16*)(ws + 67108864);           // alias: qkv[16,32MB) dead after rope_transpose

  cast_bf16_kernel<<<8192, 256, 0, stream>>>(x, xb, 2097152);
  cast_bf16_kernel<<<4096, 256, 0, stream>>>(Wq, wqkv, 1048576);
  cast_bf16_kernel<<<4096, 256, 0, stream>>>(Wk, wqkv + 2048 * 2048, 1048576);
  cast_bf16_kernel<<<4096, 256, 0, stream>>>(Wv, wqkv + 2 * 2048 * 2048, 1048576);
  cast_bf16_kernel<<<4096, 256, 0, stream>>>(Wo, wob, 1048576);
  bias_cat_kernel<<<24, 256, 0, stream>>>(bq, bk, bv, biasq);
  rope_table_kernel<<<512, 256, 0, stream>>>(cost, sint);
  // qkv = x @ [Wq|Wk|Wv]^T + bias  (4096 x 6144 x 2048)
  gemm_bt_kernel<true><<<dim3(48, 32), 256, 0, stream>>>(xb, wqkv, biasq, qkv, 4096, 6144, 2048);
  rope_transpose_kernel<<<32768, 256, 0, stream>>>(qkv, cost, sint, qr, kr, vr);
  transpose_v_kernel<<<dim3(2, 32, 32), 256, 0, stream>>>(vr, vt);
  attn_kernel<<<dim3(32, 32), 256, 0, stream>>>(qr, kr, vt, attn_out, 2048);
  // out = attn @ Wo^T + bo  (4096 x 2048 x 2048), fp32 out
  gemm_bt_kernel<false><<<dim3(16, 32), 256, 0, stream>>>(attn_out, wob, bo, (float*)d_out, 4096, 2048, 2048);
}

// Round 3
// 341.849 us; speedup vs baseline: 1.7832x; 1.5632x over previous
//
#include <hip/hip_runtime.h>
#include <math.h>

typedef __bf16 bf16;
typedef __attribute__((ext_vector_type(2))) __bf16 bf16x2;
typedef __attribute__((ext_vector_type(4))) __bf16 bf16x4;
typedef __attribute__((ext_vector_type(8))) __bf16 bf16x8;
typedef __attribute__((ext_vector_type(4))) float f32x4;

#define GLD16(g, l) __builtin_amdgcn_global_load_lds( \
    (const __attribute__((address_space(1))) void*)(g), \
    (__attribute__((address_space(3))) void*)(l), 16, 0, 0)

// ---------------- elementwise helpers ----------------

__global__ void cast_bf16_kernel(const float* __restrict__ in, bf16* __restrict__ out, int n4) {
  int i = blockIdx.x * blockDim.x + threadIdx.x;
  if (i >= n4) return;
  float4 f = ((const float4*)in)[i];
  bf16x4 o;
  o[0] = (bf16)f.x; o[1] = (bf16)f.y; o[2] = (bf16)f.z; o[3] = (bf16)f.w;
  ((bf16x4*)out)[i] = o;
}

__global__ void bias_cat_kernel(const float* __restrict__ bq, const float* __restrict__ bk,
                                const float* __restrict__ bv, float* __restrict__ out) {
  int i = blockIdx.x * blockDim.x + threadIdx.x;
  if (i >= 6144) return;
  out[i] = (i < 2048) ? bq[i] : (i < 4096 ? bk[i - 2048] : bv[i - 4096]);
}

__global__ void rope_table_kernel(float* __restrict__ cost, float* __restrict__ sint) {
  int i = blockIdx.x * blockDim.x + threadIdx.x;  // S*64 threads
  int s = i >> 6, d = i & 63;
  float inv = powf(10000.0f, -(float)d / 64.0f);
  float ang = (float)s * inv;
  cost[i] = cosf(ang);
  sint[i] = sinf(ang);
}

// qkv: (B*S, 6144) bf16 -> q_r/k_r/v_r: (B*H, S, 128) bf16 with RoPE on q,k
__global__ void rope_transpose_kernel(const bf16* __restrict__ qkv,
                                      const float* __restrict__ cost, const float* __restrict__ sint,
                                      bf16* __restrict__ qr, bf16* __restrict__ kr, bf16* __restrict__ vr) {
  int idx = blockIdx.x * blockDim.x + threadIdx.x;  // B*S*H*D = 2^23 threads
  int d = idx & 127;
  int h = (idx >> 7) & 15;
  int s = (idx >> 11) & 2047;
  int b = idx >> 22;
  const bf16* row = qkv + (size_t)(b * 2048 + s) * 6144;
  float c  = cost[(s << 6) | (d & 63)];
  float sn = sint[(s << 6) | (d & 63)];
  float qv = (float)row[(h << 7) | d];
  float qp = (float)row[(h << 7) | (d ^ 64)];
  float kv = (float)row[2048 + ((h << 7) | d)];
  float kp = (float)row[2048 + ((h << 7) | (d ^ 64))];
  float vv = (float)row[4096 + ((h << 7) | d)];
  float qrot = (d < 64) ? -qp : qp;   // rotate_half
  float krot = (d < 64) ? -kp : kp;
  size_t o = ((size_t)((b << 4) | h) * 2048 + s) * 128 + d;
  qr[o] = (bf16)(qv * c + qrot * sn);
  kr[o] = (bf16)(kv * c + krot * sn);
  vr[o] = (bf16)vv;
}

// vr: (32 bh, 2048 s, 128 d) -> vt: (32 bh, 128 d, 2048 s). LDS-tiled, both sides coalesced.
__global__ void transpose_v_kernel(const bf16* __restrict__ vr, bf16* __restrict__ vt) {
  __shared__ bf16 Vl[64 * 72];  // 64 s-rows x 64 d-cols, stride 72 breaks conflicts
  const int bh = blockIdx.z;    // 32
  const int st = blockIdx.y;    // 32
  const int dt = blockIdx.x;    // 2
  const bf16* src = vr + ((size_t)bh * 2048 + st * 64) * 128 + dt * 64;
  bf16* dst = vt + ((size_t)bh * 128 + dt * 64) * 2048 + st * 64;
  const int t = threadIdx.x;
#pragma unroll
  for (int i = 0; i < 2; ++i) {
    int c = i * 256 + t;                 // 512 chunks of 8
    int r = c >> 3, c0 = (c & 7) * 8;    // r = s index, c0 = d index
    *(bf16x8*)&Vl[r * 72 + c0] = *(const bf16x8*)&src[(size_t)r * 128 + c0];
  }
  __syncthreads();
#pragma unroll
  for (int i = 0; i < 2; ++i) {
    int c = i * 256 + t;
    int r = c >> 3, c0 = (c & 7) * 8;    // r = d index, c0 = s index
    bf16x8 v;
#pragma unroll
    for (int j = 0; j < 8; ++j) v[j] = Vl[(c0 + j) * 72 + r];
    *(bf16x8*)&dst[(size_t)r * 2048 + c0] = v;
  }
}

// ---------------- GEMM: C = A @ B^T + bias (A: MxK, B: NxK, both bf16 row-major) ----------------
// m97 structure: 128x128 tile, 4 waves 2x2, 16x16x32 bf16 MFMA, global_load_lds(16B), 2 barriers/K-step.
template<bool OUT_BF16>
__global__ __launch_bounds__(256)
void gemm_bt_kernel(const bf16* __restrict__ A, const bf16* __restrict__ B,
                    const float* __restrict__ bias, void* __restrict__ Cp,
                    int M, int N, int K) {
  __shared__ bf16 Al[128 * 32];
  __shared__ bf16 Bl[128 * 32];
  const int t = threadIdx.x;
  const int wid = t >> 6, lane = t & 63;
  const int wr = wid >> 1, wc = wid & 1;
  const int lr = lane & 15, lk = lane >> 4;
  const int tm = blockIdx.y, tn = blockIdx.x;
  const bf16* Ab = A + (size_t)tm * 128 * K;
  const bf16* Bb = B + (size_t)tn * 128 * K;
  f32x4 acc[4][4] = {};
  for (int k0 = 0; k0 < K; k0 += 32) {
    __syncthreads();  // previous tile's reads complete before overwrite
#pragma unroll
    for (int c = 0; c < 2; ++c) {
      int e = (c * 256 + t) * 8;       // flat bf16 element index in tile
      int row = e >> 5, kk = e & 31;   // [128][32] row-major
      GLD16(Ab + (size_t)row * K + k0 + kk, &Al[e]);
      GLD16(Bb + (size_t)row * K + k0 + kk, &Bl[e]);
    }
    __syncthreads();  // drains vmcnt -> LDS tiles valid
    bf16x8 af[4], bf[4];
#pragma unroll
    for (int m = 0; m < 4; ++m) af[m] = *(const bf16x8*)&Al[(wr * 64 + m * 16 + lr) * 32 + lk * 8];
#pragma unroll
    for (int n = 0; n < 4; ++n) bf[n] = *(const bf16x8*)&Bl[(wc * 64 + n * 16 + lr) * 32 + lk * 8];
#pragma unroll
    for (int m = 0; m < 4; ++m)
#pragma unroll
      for (int n = 0; n < 4; ++n)
        acc[m][n] = __builtin_amdgcn_mfma_f32_16x16x32_bf16(af[m], bf[n], acc[m][n], 0, 0, 0);
  }
  const int rb = tm * 128 + wr * 64, cb = tn * 128 + wc * 64;
#pragma unroll
  for (int n = 0; n < 4; ++n) {
    int col = cb + n * 16 + lr;      // C/D: col = lane&15
    float bvl = bias[col];
#pragma unroll
    for (int m = 0; m < 4; ++m) {
#pragma unroll
      for (int r = 0; r < 4; ++r) {
        int row = rb + m * 16 + lk * 4 + r;  // C/D: row = (lane>>4)*4 + reg
        float v = acc[m][n][r] + bvl;
        if (OUT_BF16) ((bf16*)Cp)[(size_t)row * N + col] = (bf16)v;
        else          ((float*)Cp)[(size_t)row * N + col] = v;
      }
    }
  }
}

// ---------------- causal flash attention ----------------
// Q,K: (B*H, S, 128) bf16; Vt: (B*H, 128, S) bf16 (pre-transposed). O: (B, S, H*128) bf16.
// Balanced pairing: block x handles q-tiles {x, NQ-1-x} -> every block does NQ+1 KV-tiles.
// 2-phase prefetch: double-buffered K/V LDS, next tile staged before current compute.
__global__ __launch_bounds__(256, 2)
void attn_kernel(const bf16* __restrict__ Q, const bf16* __restrict__ Kc,
                 const bf16* __restrict__ Vtg, bf16* __restrict__ O, int S) {
  __shared__ bf16 Kl[2][64 * 128];  // [kv][d], 16B chunks XOR-swizzled by kv&7 (pre-swizzled source)
  __shared__ bf16 Vt[2][128 * 64];  // [d][kv], 16B chunks XOR-swizzled by d&7 (pre-swizzled source)
  __shared__ bf16 Pl[4][16 * 64];   // per-wave P, rows XOR-swizzled by row&7
  const int t = threadIdx.x, wid = t >> 6, lane = t & 63;
  const int lr = lane & 15, lk = lane >> 4;
  const int bh = blockIdx.y;
  const int NQ = S >> 6;
  const int qtA = blockIdx.x, qtB = NQ - 1 - qtA;
  const int ntA = qtA + 1, ntB = qtB + 1, total = ntA + ntB;  // == NQ+1 for all blocks
  const bf16* Qb = Q + (size_t)bh * S * 128;
  const bf16* Kb = Kc + (size_t)bh * S * 128;
  const bf16* Vb = Vtg + (size_t)bh * 128 * S;
  const int b = bh >> 4, h = bh & 15;
  const float scale = 0.08838834764831845f;  // 1/sqrt(128)

  bf16x8 qf[4];
  auto loadQ = [&](int q0) {
    int qrow = q0 + wid * 16 + lr;
#pragma unroll
    for (int kb = 0; kb < 4; ++kb)
      qf[kb] = *(const bf16x8*)&Qb[(size_t)qrow * 128 + kb * 32 + lk * 8];
  };
  // linear LDS dest + inverse-swizzled global source (rule 21)
  auto stage = [&](int buf, int kv0) {
#pragma unroll
    for (int c = 0; c < 4; ++c) {
      int fc = c * 256 + t;
      int kvr = fc >> 4, cc = fc & 15;
      GLD16(Kb + (size_t)(kv0 + kvr) * 128 + (cc ^ (kvr & 7)) * 8, &Kl[buf][fc * 8]);
      int dr = fc >> 3, c2 = fc & 7;
      GLD16(Vb + (size_t)dr * S + kv0 + (c2 ^ (dr & 7)) * 8, &Vt[buf][fc * 8]);
    }
  };

  f32x4 o[8] = {};
  float mrun[4], lrun[4];
#pragma unroll
  for (int r = 0; r < 4; ++r) { mrun[r] = -INFINITY; lrun[r] = 0.f; }

  loadQ(qtA * 64);
  stage(0, 0);
  __syncthreads();  // tile 0 resident
  int cur = 0;
  for (int ti = 0; ti < total; ++ti) {
    // prefetch next tile into the other buffer (hidden under this tile's compute)
    if (ti + 1 < total) {
      int tn = ti + 1;
      stage(cur ^ 1, ((tn < ntA) ? tn : tn - ntA) * 64);
    }
    __builtin_amdgcn_sched_barrier(0);  // pin prefetch issue before compute
    const bool isA = ti < ntA;
    const int tt = isA ? ti : ti - ntA;
    const int nt = isA ? ntA : ntB;
    const int q0 = (isA ? qtA : qtB) * 64;
    const int kv0 = tt * 64;
    // S = Q K^T  (16x64 per wave)
    f32x4 sa[4];
    __builtin_amdgcn_s_setprio(1);
#pragma unroll
    for (int n = 0; n < 4; ++n) {
      sa[n] = (f32x4){0.f, 0.f, 0.f, 0.f};
      int kvl = n * 16 + lr;  // B-operand col
#pragma unroll
      for (int kb = 0; kb < 4; ++kb) {
        bf16x8 kf = *(const bf16x8*)&Kl[cur][kvl * 128 + (((kb << 2) | lk) ^ (kvl & 7)) * 8];
        sa[n] = __builtin_amdgcn_mfma_f32_16x16x32_bf16(qf[kb], kf, sa[n], 0, 0, 0);
      }
    }
    __builtin_amdgcn_s_setprio(0);
    // online softmax
    float p[4][4];
    float tmax[4] = {-INFINITY, -INFINITY, -INFINITY, -INFINITY};
    const bool lastTile = (tt == nt - 1);
#pragma unroll
    for (int n = 0; n < 4; ++n)
#pragma unroll
      for (int r = 0; r < 4; ++r) {
        float s = sa[n][r] * scale;
        if (lastTile) {  // only the diagonal tile needs masking
          int kvg = kv0 + n * 16 + lr;
          int qg = q0 + wid * 16 + lk * 4 + r;
          if (kvg > qg) s = -INFINITY;
        }
        p[n][r] = s;
        tmax[r] = fmaxf(tmax[r], s);
      }
#pragma unroll
    for (int r = 0; r < 4; ++r)
#pragma unroll
      for (int off = 1; off < 16; off <<= 1)
        tmax[r] = fmaxf(tmax[r], __shfl_xor(tmax[r], off));
    float alpha[4], rsum[4];
#pragma unroll
    for (int r = 0; r < 4; ++r) {
      float mnew = fmaxf(mrun[r], tmax[r]);
      alpha[r] = __expf(mrun[r] - mnew);
      mrun[r] = mnew;
      rsum[r] = 0.f;
#pragma unroll
      for (int n = 0; n < 4; ++n) {
        p[n][r] = __expf(p[n][r] - mnew);
        rsum[r] += p[n][r];
      }
    }
#pragma unroll
    for (int r = 0; r < 4; ++r) {
#pragma unroll
      for (int off = 1; off < 16; off <<= 1)
        rsum[r] += __shfl_xor(rsum[r], off);
      lrun[r] = lrun[r] * alpha[r] + rsum[r];
    }
#pragma unroll
    for (int n8 = 0; n8 < 8; ++n8)
#pragma unroll
      for (int r = 0; r < 4; ++r)
        o[n8][r] *= alpha[r];
    // write P (bf16) to per-wave LDS, row-swizzled; same-wave write->read needs only lgkmcnt
#pragma unroll
    for (int n = 0; n < 4; ++n)
#pragma unroll
      for (int r = 0; r < 4; ++r) {
        int row = lk * 4 + r, col = n * 16 + lr;
        Pl[wid][(row * 64 + col) ^ ((row & 7) << 3)] = (bf16)p[n][r];
      }
    // O += P @ V
    __builtin_amdgcn_s_setprio(1);
#pragma unroll
    for (int kb2 = 0; kb2 < 2; ++kb2) {
      bf16x8 pf = *(const bf16x8*)&Pl[wid][(lr * 64 + kb2 * 32 + lk * 8) ^ ((lr & 7) << 3)];
#pragma unroll
      for (int n8 = 0; n8 < 8; ++n8) {
        int dcol = n8 * 16 + lr;
        bf16x8 vf = *(const bf16x8*)&Vt[cur][(dcol * 64 + kb2 * 32 + lk * 8) ^ ((dcol & 7) << 3)];
        o[n8] = __builtin_amdgcn_mfma_f32_16x16x32_bf16(pf, vf, o[n8], 0, 0, 0);
      }
    }
    __builtin_amdgcn_s_setprio(0);
    // phase-A done: write O_A, reset state, load Q for phase B
    if (ti == ntA - 1) {
#pragma unroll
      for (int r = 0; r < 4; ++r) {
        float rl = 1.0f / lrun[r];
        int row = qtA * 64 + wid * 16 + lk * 4 + r;
        size_t base = ((size_t)(b * S + row)) * 2048 + h * 128;
#pragma unroll
        for (int n8 = 0; n8 < 8; ++n8)
          O[base + n8 * 16 + lr] = (bf16)(o[n8][r] * rl);
      }
#pragma unroll
      for (int n8 = 0; n8 < 8; ++n8) o[n8] = (f32x4){0.f, 0.f, 0.f, 0.f};
#pragma unroll
      for (int r = 0; r < 4; ++r) { mrun[r] = -INFINITY; lrun[r] = 0.f; }
      loadQ(qtB * 64);
    }
    __syncthreads();  // prefetched tile resident; all waves done reading buf[cur]
    cur ^= 1;
  }
  // phase-B epilogue
#pragma unroll
  for (int r = 0; r < 4; ++r) {
    float rl = 1.0f / lrun[r];
    int row = qtB * 64 + wid * 16 + lk * 4 + r;
    size_t base = ((size_t)(b * S + row)) * 2048 + h * 128;
#pragma unroll
    for (int n8 = 0; n8 < 8; ++n8)
      O[base + n8 * 16 + lr] = (bf16)(o[n8][r] * rl);
  }
}

// ---------------- launch ----------------

extern "C" void kernel_launch(void* const* d_in, const int* in_sizes, int n_in,
                              void* d_out, int out_size, void* d_ws, size_t ws_size,
                              hipStream_t stream) {
  const float* x  = (const float*)d_in[0];
  const float* Wq = (const float*)d_in[1];
  const float* bq = (const float*)d_in[2];
  const float* Wk = (const float*)d_in[3];
  const float* bk = (const float*)d_in[4];
  const float* Wv = (const float*)d_in[5];
  const float* bv = (const float*)d_in[6];
  const float* Wo = (const float*)d_in[7];
  const float* bo = (const float*)d_in[8];

  char* ws = (char*)d_ws;
  bf16* xb     = (bf16*)(ws);                  // 16 MB (x bf16; reused as q_rope after GEMM1)
  bf16* wqkv   = (bf16*)(ws + 16777216);       // 24 MB (Wq|Wk|Wv bf16, 6144x2048)
  bf16* wob    = (bf16*)(ws + 41943040);       // 8 MB
  bf16* qkv    = (bf16*)(ws + 50331648);       // 48 MB; [0,16MB) reused as attn_out, [16,32MB) as V^T
  bf16* kr     = (bf16*)(ws + 100663296);      // 16 MB
  bf16* vr     = (bf16*)(ws + 117440512);      // 16 MB (row-major V, transposed -> vt)
  float* biasq = (float*)(ws + 134217728);     // 24 KB
  float* cost  = (float*)(ws + 134242304);     // 512 KB
  float* sint  = (float*)(ws + 134766592);     // 512 KB (ws end: 135290880)
  bf16* qr = xb;                               // alias: x_bf16 dead after GEMM1
  bf16* attn_out = qkv;                        // alias: qkv[0,16MB) dead after rope_transpose
  bf16* vt = (bf16*)(ws + 67108864);           // alias: qkv[16,32MB) dead after rope_transpose

  cast_bf16_kernel<<<8192, 256, 0, stream>>>(x, xb, 2097152);
  cast_bf16_kernel<<<4096, 256, 0, stream>>>(Wq, wqkv, 1048576);
  cast_bf16_kernel<<<4096, 256, 0, stream>>>(Wk, wqkv + 2048 * 2048, 1048576);
  cast_bf16_kernel<<<4096, 256, 0, stream>>>(Wv, wqkv + 2 * 2048 * 2048, 1048576);
  cast_bf16_kernel<<<4096, 256, 0, stream>>>(Wo, wob, 1048576);
  bias_cat_kernel<<<24, 256, 0, stream>>>(bq, bk, bv, biasq);
  rope_table_kernel<<<512, 256, 0, stream>>>(cost, sint);
  // qkv = x @ [Wq|Wk|Wv]^T + bias  (4096 x 6144 x 2048)
  gemm_bt_kernel<true><<<dim3(48, 32), 256, 0, stream>>>(xb, wqkv, biasq, qkv, 4096, 6144, 2048);
  rope_transpose_kernel<<<32768, 256, 0, stream>>>(qkv, cost, sint, qr, kr, vr);
  transpose_v_kernel<<<dim3(2, 32, 32), 256, 0, stream>>>(vr, vt);
  attn_kernel<<<dim3(16, 32), 256, 0, stream>>>(qr, kr, vt, attn_out, 2048);
  // out = attn @ Wo^T + bo  (4096 x 2048 x 2048), fp32 out
  gemm_bt_kernel<false><<<dim3(16, 32), 256, 0, stream>>>(attn_out, wob, bo, (float*)d_out, 4096, 2048, 2048);
}

// Round 4
// 329.333 us; speedup vs baseline: 1.8510x; 1.0380x over previous
//
#include <hip/hip_runtime.h>
#include <math.h>

typedef __bf16 bf16;
typedef __attribute__((ext_vector_type(2))) __bf16 bf16x2;
typedef __attribute__((ext_vector_type(4))) __bf16 bf16x4;
typedef __attribute__((ext_vector_type(8))) __bf16 bf16x8;
typedef __attribute__((ext_vector_type(4))) float f32x4;

#define GLD16(g, l) __builtin_amdgcn_global_load_lds( \
    (const __attribute__((address_space(1))) void*)(g), \
    (__attribute__((address_space(3))) void*)(l), 16, 0, 0)

// ---------------- elementwise helpers ----------------

__global__ void cast_bf16_kernel(const float* __restrict__ in, bf16* __restrict__ out, int n4) {
  int i = blockIdx.x * blockDim.x + threadIdx.x;
  if (i >= n4) return;
  float4 f = ((const float4*)in)[i];
  bf16x4 o;
  o[0] = (bf16)f.x; o[1] = (bf16)f.y; o[2] = (bf16)f.z; o[3] = (bf16)f.w;
  ((bf16x4*)out)[i] = o;
}

__global__ void bias_cat_kernel(const float* __restrict__ bq, const float* __restrict__ bk,
                                const float* __restrict__ bv, float* __restrict__ out) {
  int i = blockIdx.x * blockDim.x + threadIdx.x;
  if (i >= 6144) return;
  out[i] = (i < 2048) ? bq[i] : (i < 4096 ? bk[i - 2048] : bv[i - 4096]);
}

__global__ void rope_table_kernel(float* __restrict__ cost, float* __restrict__ sint) {
  int i = blockIdx.x * blockDim.x + threadIdx.x;  // S*64 threads
  int s = i >> 6, d = i & 63;
  float inv = powf(10000.0f, -(float)d / 64.0f);
  float ang = (float)s * inv;
  cost[i] = cosf(ang);
  sint[i] = sinf(ang);
}

// qkv: (B*S, 6144) bf16 -> q_r/k_r/v_r: (B*H, S, 128) bf16 with RoPE on q,k
__global__ void rope_transpose_kernel(const bf16* __restrict__ qkv,
                                      const float* __restrict__ cost, const float* __restrict__ sint,
                                      bf16* __restrict__ qr, bf16* __restrict__ kr, bf16* __restrict__ vr) {
  int idx = blockIdx.x * blockDim.x + threadIdx.x;  // B*S*H*D = 2^23 threads
  int d = idx & 127;
  int h = (idx >> 7) & 15;
  int s = (idx >> 11) & 2047;
  int b = idx >> 22;
  const bf16* row = qkv + (size_t)(b * 2048 + s) * 6144;
  float c  = cost[(s << 6) | (d & 63)];
  float sn = sint[(s << 6) | (d & 63)];
  float qv = (float)row[(h << 7) | d];
  float qp = (float)row[(h << 7) | (d ^ 64)];
  float kv = (float)row[2048 + ((h << 7) | d)];
  float kp = (float)row[2048 + ((h << 7) | (d ^ 64))];
  float vv = (float)row[4096 + ((h << 7) | d)];
  float qrot = (d < 64) ? -qp : qp;   // rotate_half
  float krot = (d < 64) ? -kp : kp;
  size_t o = ((size_t)((b << 4) | h) * 2048 + s) * 128 + d;
  qr[o] = (bf16)(qv * c + qrot * sn);
  kr[o] = (bf16)(kv * c + krot * sn);
  vr[o] = (bf16)vv;
}

// vr: (32 bh, 2048 s, 128 d) -> vt: (32 bh, 128 d, 2048 s). LDS-tiled, both sides coalesced.
__global__ void transpose_v_kernel(const bf16* __restrict__ vr, bf16* __restrict__ vt) {
  __shared__ bf16 Vl[64 * 72];  // 64 s-rows x 64 d-cols, stride 72 breaks conflicts
  const int bh = blockIdx.z;    // 32
  const int st = blockIdx.y;    // 32
  const int dt = blockIdx.x;    // 2
  const bf16* src = vr + ((size_t)bh * 2048 + st * 64) * 128 + dt * 64;
  bf16* dst = vt + ((size_t)bh * 128 + dt * 64) * 2048 + st * 64;
  const int t = threadIdx.x;
#pragma unroll
  for (int i = 0; i < 2; ++i) {
    int c = i * 256 + t;                 // 512 chunks of 8
    int r = c >> 3, c0 = (c & 7) * 8;    // r = s index, c0 = d index
    *(bf16x8*)&Vl[r * 72 + c0] = *(const bf16x8*)&src[(size_t)r * 128 + c0];
  }
  __syncthreads();
#pragma unroll
  for (int i = 0; i < 2; ++i) {
    int c = i * 256 + t;
    int r = c >> 3, c0 = (c & 7) * 8;    // r = d index, c0 = s index
    bf16x8 v;
#pragma unroll
    for (int j = 0; j < 8; ++j) v[j] = Vl[(c0 + j) * 72 + r];
    *(bf16x8*)&dst[(size_t)r * 2048 + c0] = v;
  }
}

// ---------------- GEMM 128^2 (m97 structure) — kept for the out-projection ----------------
template<bool OUT_BF16>
__global__ __launch_bounds__(256)
void gemm_bt_kernel(const bf16* __restrict__ A, const bf16* __restrict__ B,
                    const float* __restrict__ bias, void* __restrict__ Cp,
                    int M, int N, int K) {
  __shared__ bf16 Al[128 * 32];
  __shared__ bf16 Bl[128 * 32];
  const int t = threadIdx.x;
  const int wid = t >> 6, lane = t & 63;
  const int wr = wid >> 1, wc = wid & 1;
  const int lr = lane & 15, lk = lane >> 4;
  const int tm = blockIdx.y, tn = blockIdx.x;
  const bf16* Ab = A + (size_t)tm * 128 * K;
  const bf16* Bb = B + (size_t)tn * 128 * K;
  f32x4 acc[4][4] = {};
  for (int k0 = 0; k0 < K; k0 += 32) {
    __syncthreads();
#pragma unroll
    for (int c = 0; c < 2; ++c) {
      int e = (c * 256 + t) * 8;
      int row = e >> 5, kk = e & 31;
      GLD16(Ab + (size_t)row * K + k0 + kk, &Al[e]);
      GLD16(Bb + (size_t)row * K + k0 + kk, &Bl[e]);
    }
    __syncthreads();
    bf16x8 af[4], bf[4];
#pragma unroll
    for (int m = 0; m < 4; ++m) af[m] = *(const bf16x8*)&Al[(wr * 64 + m * 16 + lr) * 32 + lk * 8];
#pragma unroll
    for (int n = 0; n < 4; ++n) bf[n] = *(const bf16x8*)&Bl[(wc * 64 + n * 16 + lr) * 32 + lk * 8];
#pragma unroll
    for (int m = 0; m < 4; ++m)
#pragma unroll
      for (int n = 0; n < 4; ++n)
        acc[m][n] = __builtin_amdgcn_mfma_f32_16x16x32_bf16(af[m], bf[n], acc[m][n], 0, 0, 0);
  }
  const int rb = tm * 128 + wr * 64, cb = tn * 128 + wc * 64;
#pragma unroll
  for (int n = 0; n < 4; ++n) {
    int col = cb + n * 16 + lr;
    float bvl = bias[col];
#pragma unroll
    for (int m = 0; m < 4; ++m) {
#pragma unroll
      for (int r = 0; r < 4; ++r) {
        int row = rb + m * 16 + lk * 4 + r;
        float v = acc[m][n][r] + bvl;
        if (OUT_BF16) ((bf16*)Cp)[(size_t)row * N + col] = (bf16)v;
        else          ((float*)Cp)[(size_t)row * N + col] = v;
      }
    }
  }
}

// ---------------- GEMM 256^2 8-phase (m201 template): C = A @ B^T + bias ----------------
// 512 thr / 8 waves (2M x 4N), BK=64, 128 KiB LDS (2 dbuf x 2 halves x {A,B}).
// Per K-tile: 4 phases x 16 MFMA. Counted vmcnt(4) once per tile (never 0 mid-loop).
// Stage schedule (tile u, buf p=u&1): ph0: a0(u+1)->p^1, ph1: a1(u+1)->p^1,
// ph2: b0(u+2)->p, ph3: b1(u+2)->p. Every target half was last read >=1 barrier earlier.
// LDS halves [128][64] bf16, 16B-chunk XOR swizzle: LDS[r][c] holds global chunk c^(r&7).
template<bool OUT_BF16>
__global__ __launch_bounds__(512, 2)
void gemm256_kernel(const bf16* __restrict__ A, const bf16* __restrict__ B,
                    const float* __restrict__ bias, void* __restrict__ Cp,
                    int M, int N, int K) {
  __shared__ bf16 Al[2][2][128 * 64];
  __shared__ bf16 Bl[2][2][128 * 64];
  const int t = threadIdx.x;
  const int wid = t >> 6, lane = t & 63;
  const int wr = wid >> 2, wc = wid & 3;
  const int lr = lane & 15, lk = lane >> 4;
  const int tm = blockIdx.y, tn = blockIdx.x;
  const bf16* Ab = A + (size_t)tm * 256 * K;
  const bf16* Bb = B + (size_t)tn * 256 * K;
  const int NT = K >> 6;

  // stage one 128x64 half (16 KB): 2 GLD16/thread; linear LDS dest + inverse-swizzled source
  auto stageA = [&](int bp, int h, int kt) {
#pragma unroll
    for (int q = 0; q < 2; ++q) {
      int e = q * 512 + t;
      int r = e >> 3, c = e & 7;
      GLD16(Ab + (size_t)(h * 128 + r) * K + kt * 64 + ((c ^ (r & 7)) << 3), &Al[bp][h][e * 8]);
    }
  };
  auto stageB = [&](int bp, int h, int kt) {
#pragma unroll
    for (int q = 0; q < 2; ++q) {
      int e = q * 512 + t;
      int r = e >> 3, c = e & 7;
      GLD16(Bb + (size_t)(h * 128 + r) * K + kt * 64 + ((c ^ (r & 7)) << 3), &Bl[bp][h][e * 8]);
    }
  };

  f32x4 acc[8][4] = {};

  // prologue: tile0 fully, tile1 b-halves; vmcnt(4) allows b(1) to stay in flight
  stageB(0, 0, 0); stageB(0, 1, 0);
  stageA(0, 0, 0); stageA(0, 1, 0);
  if (NT > 1) { stageB(1, 0, 1); stageB(1, 1, 1); }
  asm volatile("s_waitcnt vmcnt(4)" ::: "memory");
  __builtin_amdgcn_s_barrier();
  __builtin_amdgcn_sched_barrier(0);

  for (int u = 0; u < NT; ++u) {
    const int p = u & 1;
    const bf16* Ah = Al[p][wr];
    const bf16* Bh = Bl[p][wc >> 1];
    const int rb0 = (wc & 1) * 64;
    bf16x8 bfr[4][2];
#pragma unroll
    for (int j = 0; j < 4; ++j) {
      bf16x8 afr[2][2];
      if (j == 0) {
#pragma unroll
        for (int n = 0; n < 4; ++n)
#pragma unroll
          for (int kk = 0; kk < 2; ++kk) {
            int r = rb0 + n * 16 + lr;
            bfr[n][kk] = *(const bf16x8*)&Bh[r * 64 + ((((kk << 2) | lk) ^ (r & 7)) << 3)];
          }
      }
#pragma unroll
      for (int m2 = 0; m2 < 2; ++m2)
#pragma unroll
        for (int kk = 0; kk < 2; ++kk) {
          int r = (2 * j + m2) * 16 + lr;
          afr[m2][kk] = *(const bf16x8*)&Ah[r * 64 + ((((kk << 2) | lk) ^ (r & 7)) << 3)];
        }
      // stage one half-tile (targets freed >=1 barrier ago)
      if (j == 0)      { if (u + 1 < NT) stageA(p ^ 1, 0, u + 1); }
      else if (j == 1) { if (u + 1 < NT) stageA(p ^ 1, 1, u + 1); }
      else if (j == 2) { if (u + 2 < NT) stageB(p, 0, u + 2); }
      else             { if (u + 2 < NT) stageB(p, 1, u + 2); }
      __builtin_amdgcn_s_barrier();
      asm volatile("s_waitcnt lgkmcnt(0)" ::: "memory");
      __builtin_amdgcn_sched_barrier(0);
      __builtin_amdgcn_s_setprio(1);
#pragma unroll
      for (int m2 = 0; m2 < 2; ++m2)
#pragma unroll
        for (int n = 0; n < 4; ++n)
#pragma unroll
          for (int kk = 0; kk < 2; ++kk)
            acc[2 * j + m2][n] = __builtin_amdgcn_mfma_f32_16x16x32_bf16(
                afr[m2][kk], bfr[n][kk], acc[2 * j + m2][n], 0, 0, 0);
      __builtin_amdgcn_s_setprio(0);
      __builtin_amdgcn_sched_barrier(0);
      if (j == 3) {
        if (u + 2 < NT) { asm volatile("s_waitcnt vmcnt(4)" ::: "memory"); }
        else            { asm volatile("s_waitcnt vmcnt(0)" ::: "memory"); }
      }
      __builtin_amdgcn_s_barrier();
      __builtin_amdgcn_sched_barrier(0);
    }
  }

  const int rb = tm * 256 + wr * 128, cb = tn * 256 + wc * 64;
#pragma unroll
  for (int n = 0; n < 4; ++n) {
    int col = cb + n * 16 + lr;
    float bvl = bias[col];
#pragma unroll
    for (int m = 0; m < 8; ++m) {
#pragma unroll
      for (int r = 0; r < 4; ++r) {
        int row = rb + m * 16 + lk * 4 + r;
        float v = acc[m][n][r] + bvl;
        if (OUT_BF16) ((bf16*)Cp)[(size_t)row * N + col] = (bf16)v;
        else          ((float*)Cp)[(size_t)row * N + col] = v;
      }
    }
  }
}

// ---------------- causal flash attention ----------------
// Q,K: (B*H, S, 128) bf16; Vt: (B*H, 128, S) bf16 (pre-transposed). O: (B, S, H*128) bf16.
// Balanced pairing: block x handles q-tiles {x, NQ-1-x} -> every block does NQ+1 KV-tiles.
// 2-phase prefetch: double-buffered K/V LDS, next tile staged before current compute.
__global__ __launch_bounds__(256, 2)
void attn_kernel(const bf16* __restrict__ Q, const bf16* __restrict__ Kc,
                 const bf16* __restrict__ Vtg, bf16* __restrict__ O, int S) {
  __shared__ bf16 Kl[2][64 * 128];  // [kv][d], 16B chunks XOR-swizzled by kv&7 (pre-swizzled source)
  __shared__ bf16 Vt[2][128 * 64];  // [d][kv], 16B chunks XOR-swizzled by d&7 (pre-swizzled source)
  __shared__ bf16 Pl[4][16 * 64];   // per-wave P, rows XOR-swizzled by row&7
  const int t = threadIdx.x, wid = t >> 6, lane = t & 63;
  const int lr = lane & 15, lk = lane >> 4;
  const int bh = blockIdx.y;
  const int NQ = S >> 6;
  const int qtA = blockIdx.x, qtB = NQ - 1 - qtA;
  const int ntA = qtA + 1, ntB = qtB + 1, total = ntA + ntB;  // == NQ+1 for all blocks
  const bf16* Qb = Q + (size_t)bh * S * 128;
  const bf16* Kb = Kc + (size_t)bh * S * 128;
  const bf16* Vb = Vtg + (size_t)bh * 128 * S;
  const int b = bh >> 4, h = bh & 15;
  const float scale = 0.08838834764831845f;  // 1/sqrt(128)

  bf16x8 qf[4];
  auto loadQ = [&](int q0) {
    int qrow = q0 + wid * 16 + lr;
#pragma unroll
    for (int kb = 0; kb < 4; ++kb)
      qf[kb] = *(const bf16x8*)&Qb[(size_t)qrow * 128 + kb * 32 + lk * 8];
  };
  auto stage = [&](int buf, int kv0) {
#pragma unroll
    for (int c = 0; c < 4; ++c) {
      int fc = c * 256 + t;
      int kvr = fc >> 4, cc = fc & 15;
      GLD16(Kb + (size_t)(kv0 + kvr) * 128 + (cc ^ (kvr & 7)) * 8, &Kl[buf][fc * 8]);
      int dr = fc >> 3, c2 = fc & 7;
      GLD16(Vb + (size_t)dr * S + kv0 + (c2 ^ (dr & 7)) * 8, &Vt[buf][fc * 8]);
    }
  };

  f32x4 o[8] = {};
  float mrun[4], lrun[4];
#pragma unroll
  for (int r = 0; r < 4; ++r) { mrun[r] = -INFINITY; lrun[r] = 0.f; }

  loadQ(qtA * 64);
  stage(0, 0);
  __syncthreads();  // tile 0 resident
  int cur = 0;
  for (int ti = 0; ti < total; ++ti) {
    if (ti + 1 < total) {
      int tn = ti + 1;
      stage(cur ^ 1, ((tn < ntA) ? tn : tn - ntA) * 64);
    }
    __builtin_amdgcn_sched_barrier(0);
    const bool isA = ti < ntA;
    const int tt = isA ? ti : ti - ntA;
    const int nt = isA ? ntA : ntB;
    const int q0 = (isA ? qtA : qtB) * 64;
    const int kv0 = tt * 64;
    f32x4 sa[4];
    __builtin_amdgcn_s_setprio(1);
#pragma unroll
    for (int n = 0; n < 4; ++n) {
      sa[n] = (f32x4){0.f, 0.f, 0.f, 0.f};
      int kvl = n * 16 + lr;
#pragma unroll
      for (int kb = 0; kb < 4; ++kb) {
        bf16x8 kf = *(const bf16x8*)&Kl[cur][kvl * 128 + (((kb << 2) | lk) ^ (kvl & 7)) * 8];
        sa[n] = __builtin_amdgcn_mfma_f32_16x16x32_bf16(qf[kb], kf, sa[n], 0, 0, 0);
      }
    }
    __builtin_amdgcn_s_setprio(0);
    float p[4][4];
    float tmax[4] = {-INFINITY, -INFINITY, -INFINITY, -INFINITY};
    const bool lastTile = (tt == nt - 1);
#pragma unroll
    for (int n = 0; n < 4; ++n)
#pragma unroll
      for (int r = 0; r < 4; ++r) {
        float s = sa[n][r] * scale;
        if (lastTile) {
          int kvg = kv0 + n * 16 + lr;
          int qg = q0 + wid * 16 + lk * 4 + r;
          if (kvg > qg) s = -INFINITY;
        }
        p[n][r] = s;
        tmax[r] = fmaxf(tmax[r], s);
      }
#pragma unroll
    for (int r = 0; r < 4; ++r)
#pragma unroll
      for (int off = 1; off < 16; off <<= 1)
        tmax[r] = fmaxf(tmax[r], __shfl_xor(tmax[r], off));
    float alpha[4], rsum[4];
#pragma unroll
    for (int r = 0; r < 4; ++r) {
      float mnew = fmaxf(mrun[r], tmax[r]);
      alpha[r] = __expf(mrun[r] - mnew);
      mrun[r] = mnew;
      rsum[r] = 0.f;
#pragma unroll
      for (int n = 0; n < 4; ++n) {
        p[n][r] = __expf(p[n][r] - mnew);
        rsum[r] += p[n][r];
      }
    }
#pragma unroll
    for (int r = 0; r < 4; ++r) {
#pragma unroll
      for (int off = 1; off < 16; off <<= 1)
        rsum[r] += __shfl_xor(rsum[r], off);
      lrun[r] = lrun[r] * alpha[r] + rsum[r];
    }
#pragma unroll
    for (int n8 = 0; n8 < 8; ++n8)
#pragma unroll
      for (int r = 0; r < 4; ++r)
        o[n8][r] *= alpha[r];
#pragma unroll
    for (int n = 0; n < 4; ++n)
#pragma unroll
      for (int r = 0; r < 4; ++r) {
        int row = lk * 4 + r, col = n * 16 + lr;
        Pl[wid][(row * 64 + col) ^ ((row & 7) << 3)] = (bf16)p[n][r];
      }
    __builtin_amdgcn_s_setprio(1);
#pragma unroll
    for (int kb2 = 0; kb2 < 2; ++kb2) {
      bf16x8 pf = *(const bf16x8*)&Pl[wid][(lr * 64 + kb2 * 32 + lk * 8) ^ ((lr & 7) << 3)];
#pragma unroll
      for (int n8 = 0; n8 < 8; ++n8) {
        int dcol = n8 * 16 + lr;
        bf16x8 vf = *(const bf16x8*)&Vt[cur][(dcol * 64 + kb2 * 32 + lk * 8) ^ ((dcol & 7) << 3)];
        o[n8] = __builtin_amdgcn_mfma_f32_16x16x32_bf16(pf, vf, o[n8], 0, 0, 0);
      }
    }
    __builtin_amdgcn_s_setprio(0);
    if (ti == ntA - 1) {
#pragma unroll
      for (int r = 0; r < 4; ++r) {
        float rl = 1.0f / lrun[r];
        int row = qtA * 64 + wid * 16 + lk * 4 + r;
        size_t base = ((size_t)(b * S + row)) * 2048 + h * 128;
#pragma unroll
        for (int n8 = 0; n8 < 8; ++n8)
          O[base + n8 * 16 + lr] = (bf16)(o[n8][r] * rl);
      }
#pragma unroll
      for (int n8 = 0; n8 < 8; ++n8) o[n8] = (f32x4){0.f, 0.f, 0.f, 0.f};
#pragma unroll
      for (int r = 0; r < 4; ++r) { mrun[r] = -INFINITY; lrun[r] = 0.f; }
      loadQ(qtB * 64);
    }
    __syncthreads();
    cur ^= 1;
  }
#pragma unroll
  for (int r = 0; r < 4; ++r) {
    float rl = 1.0f / lrun[r];
    int row = qtB * 64 + wid * 16 + lk * 4 + r;
    size_t base = ((size_t)(b * S + row)) * 2048 + h * 128;
#pragma unroll
    for (int n8 = 0; n8 < 8; ++n8)
      O[base + n8 * 16 + lr] = (bf16)(o[n8][r] * rl);
  }
}

// ---------------- launch ----------------

extern "C" void kernel_launch(void* const* d_in, const int* in_sizes, int n_in,
                              void* d_out, int out_size, void* d_ws, size_t ws_size,
                              hipStream_t stream) {
  const float* x  = (const float*)d_in[0];
  const float* Wq = (const float*)d_in[1];
  const float* bq = (const float*)d_in[2];
  const float* Wk = (const float*)d_in[3];
  const float* bk = (const float*)d_in[4];
  const float* Wv = (const float*)d_in[5];
  const float* bv = (const float*)d_in[6];
  const float* Wo = (const float*)d_in[7];
  const float* bo = (const float*)d_in[8];

  char* ws = (char*)d_ws;
  bf16* xb     = (bf16*)(ws);                  // 16 MB (x bf16; reused as q_rope after GEMM1)
  bf16* wqkv   = (bf16*)(ws + 16777216);       // 24 MB (Wq|Wk|Wv bf16, 6144x2048)
  bf16* wob    = (bf16*)(ws + 41943040);       // 8 MB
  bf16* qkv    = (bf16*)(ws + 50331648);       // 48 MB; [0,16MB) reused as attn_out, [16,32MB) as V^T
  bf16* kr     = (bf16*)(ws + 100663296);      // 16 MB
  bf16* vr     = (bf16*)(ws + 117440512);      // 16 MB (row-major V, transposed -> vt)
  float* biasq = (float*)(ws + 134217728);     // 24 KB
  float* cost  = (float*)(ws + 134242304);     // 512 KB
  float* sint  = (float*)(ws + 134766592);     // 512 KB (ws end: 135290880)
  bf16* qr = xb;                               // alias: x_bf16 dead after GEMM1
  bf16* attn_out = qkv;                        // alias: qkv[0,16MB) dead after rope_transpose
  bf16* vt = (bf16*)(ws + 67108864);           // alias: qkv[16,32MB) dead after rope_transpose

  cast_bf16_kernel<<<8192, 256, 0, stream>>>(x, xb, 2097152);
  cast_bf16_kernel<<<4096, 256, 0, stream>>>(Wq, wqkv, 1048576);
  cast_bf16_kernel<<<4096, 256, 0, stream>>>(Wk, wqkv + 2048 * 2048, 1048576);
  cast_bf16_kernel<<<4096, 256, 0, stream>>>(Wv, wqkv + 2 * 2048 * 2048, 1048576);
  cast_bf16_kernel<<<4096, 256, 0, stream>>>(Wo, wob, 1048576);
  bias_cat_kernel<<<24, 256, 0, stream>>>(bq, bk, bv, biasq);
  rope_table_kernel<<<512, 256, 0, stream>>>(cost, sint);
  // qkv = x @ [Wq|Wk|Wv]^T + bias  (4096 x 6144 x 2048)  — 256^2 8-phase
  gemm256_kernel<true><<<dim3(24, 16), 512, 0, stream>>>(xb, wqkv, biasq, qkv, 4096, 6144, 2048);
  rope_transpose_kernel<<<32768, 256, 0, stream>>>(qkv, cost, sint, qr, kr, vr);
  transpose_v_kernel<<<dim3(2, 32, 32), 256, 0, stream>>>(vr, vt);
  attn_kernel<<<dim3(16, 32), 256, 0, stream>>>(qr, kr, vt, attn_out, 2048);
  // out = attn @ Wo^T + bo  (4096 x 2048 x 2048), fp32 out — 128^2 (exact 2 rounds)
  gemm_bt_kernel<false><<<dim3(16, 32), 256, 0, stream>>>(attn_out, wob, bo, (float*)d_out, 4096, 2048, 2048);
}

// Round 5
// 299.187 us; speedup vs baseline: 2.0375x; 1.1008x over previous
//
#include <hip/hip_runtime.h>
#include <math.h>

typedef __bf16 bf16;
typedef __attribute__((ext_vector_type(2))) __bf16 bf16x2;
typedef __attribute__((ext_vector_type(4))) __bf16 bf16x4;
typedef __attribute__((ext_vector_type(8))) __bf16 bf16x8;
typedef __attribute__((ext_vector_type(4))) float f32x4;

#define GLD16(g, l) __builtin_amdgcn_global_load_lds( \
    (const __attribute__((address_space(1))) void*)(g), \
    (__attribute__((address_space(3))) void*)(l), 16, 0, 0)

template<int N> __device__ __forceinline__ void wait_vm() {
  static_assert(N == 0 || N == 2 || N == 3 || N == 4, "");
  if constexpr (N == 0) asm volatile("s_waitcnt vmcnt(0)" ::: "memory");
  else if constexpr (N == 2) asm volatile("s_waitcnt vmcnt(2)" ::: "memory");
  else if constexpr (N == 3) asm volatile("s_waitcnt vmcnt(3)" ::: "memory");
  else asm volatile("s_waitcnt vmcnt(4)" ::: "memory");
}

// ---------------- fused prologue: casts + bias concat + rope table ----------------
// regions (blocks of 256 thr): [0,8192) x | [8192,12288) Wq | [12288,16384) Wk |
// [16384,20480) Wv | [20480,24576) Wo | [24576,25088) rope table | [25088,25112) bias
__global__ void prep_kernel(const float* __restrict__ x,
                            const float* __restrict__ Wq, const float* __restrict__ Wk,
                            const float* __restrict__ Wv, const float* __restrict__ Wo,
                            const float* __restrict__ bq, const float* __restrict__ bk,
                            const float* __restrict__ bv,
                            bf16* __restrict__ xb, bf16* __restrict__ wqkv, bf16* __restrict__ wob,
                            float* __restrict__ biasq, float* __restrict__ cost, float* __restrict__ sint) {
  const int bid = blockIdx.x, t = threadIdx.x;
  if (bid < 24576) {
    const float* src;
    bf16* dst;
    int i;
    if (bid < 8192)       { src = x;  dst = xb;                    i = bid * 256 + t; }
    else if (bid < 12288) { src = Wq; dst = wqkv;                  i = (bid - 8192) * 256 + t; }
    else if (bid < 16384) { src = Wk; dst = wqkv + 2048 * 2048;    i = (bid - 12288) * 256 + t; }
    else if (bid < 20480) { src = Wv; dst = wqkv + 2 * 2048 * 2048; i = (bid - 16384) * 256 + t; }
    else                  { src = Wo; dst = wob;                   i = (bid - 20480) * 256 + t; }
    float4 f = ((const float4*)src)[i];
    bf16x4 o;
    o[0] = (bf16)f.x; o[1] = (bf16)f.y; o[2] = (bf16)f.z; o[3] = (bf16)f.w;
    ((bf16x4*)dst)[i] = o;
  } else if (bid < 25088) {
    int i = (bid - 24576) * 256 + t;  // S*64
    int s = i >> 6, d = i & 63;
    float inv = powf(10000.0f, -(float)d / 64.0f);
    float ang = (float)s * inv;
    cost[i] = cosf(ang);
    sint[i] = sinf(ang);
  } else {
    int i = (bid - 25088) * 256 + t;  // 6144
    biasq[i] = (i < 2048) ? bq[i] : (i < 4096 ? bk[i - 2048] : bv[i - 4096]);
  }
}

// ---------------- RoPE on K only: qkv -> kr (B*H, S, 128) ----------------
__global__ void rope_k_kernel(const bf16* __restrict__ qkv,
                              const float* __restrict__ cost, const float* __restrict__ sint,
                              bf16* __restrict__ kr) {
  int idx = blockIdx.x * blockDim.x + threadIdx.x;  // (b,s,h,dp), dp<16 -> d0=dp*4
  int dp = idx & 15;
  int h = (idx >> 4) & 15;
  int s = (idx >> 8) & 2047;
  int b = idx >> 19;
  int d0 = dp * 4;
  const bf16* row = qkv + ((size_t)(b * 2048 + s) * 6144) + 2048 + h * 128;
  bf16x4 klo = *(const bf16x4*)&row[d0];
  bf16x4 khi = *(const bf16x4*)&row[d0 + 64];
  float4 c4 = *(const float4*)&cost[(s << 6) + d0];
  float4 s4 = *(const float4*)&sint[(s << 6) + d0];
  float cf[4] = {c4.x, c4.y, c4.z, c4.w};
  float sf[4] = {s4.x, s4.y, s4.z, s4.w};
  bf16x4 olo, ohi;
#pragma unroll
  for (int j = 0; j < 4; ++j) {
    float kl = (float)klo[j], kh = (float)khi[j];
    olo[j] = (bf16)(kl * cf[j] - kh * sf[j]);   // d<64: rot = -k[d+64]
    ohi[j] = (bf16)(kh * cf[j] + kl * sf[j]);   // d>=64: rot = +k[d-64]
  }
  bf16* orow = kr + (((size_t)(b * 16 + h) * 2048 + s) * 128);
  *(bf16x4*)&orow[d0] = olo;
  *(bf16x4*)&orow[d0 + 64] = ohi;
}

// V section of qkv: (b,s) rows, cols 4096 + h*128 + d -> vt: (32 bh, 128 d, 2048 s)
__global__ void transpose_v_kernel(const bf16* __restrict__ qkv, bf16* __restrict__ vt) {
  __shared__ bf16 Vl[64 * 72];  // 64 s-rows x 64 d-cols, stride 72 breaks conflicts
  const int bh = blockIdx.z;    // 32
  const int st = blockIdx.y;    // 32
  const int dt = blockIdx.x;    // 2
  const int b = bh >> 4, h = bh & 15;
  const bf16* src = qkv + ((size_t)(b * 2048 + st * 64) * 6144) + 4096 + h * 128 + dt * 64;
  bf16* dst = vt + ((size_t)bh * 128 + dt * 64) * 2048 + st * 64;
  const int t = threadIdx.x;
#pragma unroll
  for (int i = 0; i < 2; ++i) {
    int c = i * 256 + t;
    int r = c >> 3, c0 = (c & 7) * 8;    // r = s index, c0 = d index
    *(bf16x8*)&Vl[r * 72 + c0] = *(const bf16x8*)&src[(size_t)r * 6144 + c0];
  }
  __syncthreads();
#pragma unroll
  for (int i = 0; i < 2; ++i) {
    int c = i * 256 + t;
    int r = c >> 3, c0 = (c & 7) * 8;    // r = d index, c0 = s index
    bf16x8 v;
#pragma unroll
    for (int j = 0; j < 8; ++j) v[j] = Vl[(c0 + j) * 72 + r];
    *(bf16x8*)&dst[(size_t)r * 2048 + c0] = v;
  }
}

// ---------------- GEMM 256xBN 8-phase (m201 template): C = A @ B^T + bias ----------------
// 512 thr / 8 waves (2M x 4N), BK=64. A: 2 units of 128x64; B: NB=BN/64 units of 64x64.
// Per K-tile: 4 phases x (4*NB) MFMA. Counted vmcnt(NB) once per tile (never 0 mid-loop).
// Stage: ph0/ph1 -> A halves (u+1) into buf p^1; ph2/ph3 -> B units (u+2) into buf p.
// LDS rows of 64 bf16; 16B-chunk XOR swizzle: LDS[r][c] holds global chunk c^(r&7).
template<int BN, bool OUT_BF16, int LOGNX>
__global__ __launch_bounds__(512, 2)
void gemm256_kernel(const bf16* __restrict__ A, const bf16* __restrict__ B,
                    const float* __restrict__ bias, void* __restrict__ Cp,
                    int M, int N, int K) {
  constexpr int NB = BN / 64;
  __shared__ bf16 Al[2][2][128 * 64];
  __shared__ bf16 Bl[2][NB][64 * 64];
  const int t = threadIdx.x;
  const int wid = t >> 6, lane = t & 63;
  const int wr = wid >> 2, wc = wid & 3;
  const int lr = lane & 15, lk = lane >> 4;
  // bijective XCD swizzle (nwg % 8 == 0)
  const int nwg = (int)(gridDim.x * gridDim.y);
  const int flat = (int)(blockIdx.y * gridDim.x + blockIdx.x);
  const int fs = (flat & 7) * (nwg >> 3) + (flat >> 3);
  const int tn = fs & ((1 << LOGNX) - 1);
  const int tm = fs >> LOGNX;
  const bf16* Ab = A + (size_t)tm * 256 * K;
  const bf16* Bb = B + (size_t)tn * BN * K;
  const int NT = K >> 6;

  auto stageA = [&](int bp, int h, int kt) {
#pragma unroll
    for (int q = 0; q < 2; ++q) {
      int e = q * 512 + t;
      int r = e >> 3, c = e & 7;
      GLD16(Ab + (size_t)(h * 128 + r) * K + kt * 64 + ((c ^ (r & 7)) << 3), &Al[bp][h][e * 8]);
    }
  };
  auto stageB = [&](int bp, int unit, int kt) {
    int r = t >> 3, c = t & 7;  // 512 thr x 16B = one 64x64 unit
    GLD16(Bb + (size_t)(unit * 64 + r) * K + kt * 64 + ((c ^ (r & 7)) << 3), &Bl[bp][unit][t * 8]);
  };

  f32x4 acc[8][NB] = {};

  // prologue: b(0), a(0), b(1); leave b(1) in flight
#pragma unroll
  for (int un = 0; un < NB; ++un) stageB(0, un, 0);
  stageA(0, 0, 0); stageA(0, 1, 0);
  if (NT > 1) {
#pragma unroll
    for (int un = 0; un < NB; ++un) stageB(1, un, 1);
    wait_vm<NB>();
  } else {
    wait_vm<0>();
  }
  __builtin_amdgcn_s_barrier();
  __builtin_amdgcn_sched_barrier(0);

  for (int u = 0; u < NT; ++u) {
    const int p = u & 1;
    const bf16* Ah = Al[p][wr];
    bf16x8 bfr[NB][2];
#pragma unroll
    for (int j = 0; j < 4; ++j) {
      bf16x8 afr[2][2];
      if (j == 0) {
#pragma unroll
        for (int n = 0; n < NB; ++n)
#pragma unroll
          for (int kk = 0; kk < 2; ++kk) {
            int rb = wc * (NB * 16) + n * 16 + lr;
            bfr[n][kk] = *(const bf16x8*)&Bl[p][rb >> 6][(rb & 63) * 64 + ((((kk << 2) | lk) ^ (rb & 7)) << 3)];
          }
      }
#pragma unroll
      for (int m2 = 0; m2 < 2; ++m2)
#pragma unroll
        for (int kk = 0; kk < 2; ++kk) {
          int r = (2 * j + m2) * 16 + lr;
          afr[m2][kk] = *(const bf16x8*)&Ah[r * 64 + ((((kk << 2) | lk) ^ (r & 7)) << 3)];
        }
      // stage one unit-group (targets freed >=1 barrier ago)
      if (j == 0)      { if (u + 1 < NT) stageA(p ^ 1, 0, u + 1); }
      else if (j == 1) { if (u + 1 < NT) stageA(p ^ 1, 1, u + 1); }
      else if (j == 2) {
        if (u + 2 < NT) {
#pragma unroll
          for (int un = 0; un < NB / 2; ++un) stageB(p, un, u + 2);
        }
      } else {
        if (u + 2 < NT) {
#pragma unroll
          for (int un = NB / 2; un < NB; ++un) stageB(p, un, u + 2);
        }
      }
      __builtin_amdgcn_s_barrier();
      asm volatile("s_waitcnt lgkmcnt(0)" ::: "memory");
      __builtin_amdgcn_sched_barrier(0);
      __builtin_amdgcn_s_setprio(1);
#pragma unroll
      for (int m2 = 0; m2 < 2; ++m2)
#pragma unroll
        for (int n = 0; n < NB; ++n)
#pragma unroll
          for (int kk = 0; kk < 2; ++kk)
            acc[2 * j + m2][n] = __builtin_amdgcn_mfma_f32_16x16x32_bf16(
                afr[m2][kk], bfr[n][kk], acc[2 * j + m2][n], 0, 0, 0);
      __builtin_amdgcn_s_setprio(0);
      __builtin_amdgcn_sched_barrier(0);
      if (j == 3) {
        if (u + 2 < NT) { wait_vm<NB>(); }
        else            { wait_vm<0>(); }
      }
      __builtin_amdgcn_s_barrier();
      __builtin_amdgcn_sched_barrier(0);
    }
  }

  const int rb = tm * 256 + wr * 128, cb = tn * BN + wc * (NB * 16);
#pragma unroll
  for (int n = 0; n < NB; ++n) {
    int col = cb + n * 16 + lr;
    float bvl = bias[col];
#pragma unroll
    for (int m = 0; m < 8; ++m) {
#pragma unroll
      for (int r = 0; r < 4; ++r) {
        int row = rb + m * 16 + lk * 4 + r;
        float v = acc[m][n][r] + bvl;
        if (OUT_BF16) ((bf16*)Cp)[(size_t)row * N + col] = (bf16)v;
        else          ((float*)Cp)[(size_t)row * N + col] = v;
      }
    }
  }
}

// ---------------- causal flash attention ----------------
// Q read directly from qkv (RoPE applied in-register); K from kr; V^T from vt.
// O: (B, S, H*128) bf16. Balanced pairing + 2-phase double-buffered prefetch.
__global__ __launch_bounds__(256, 2)
void attn_kernel(const bf16* __restrict__ qkv, const bf16* __restrict__ Kc,
                 const bf16* __restrict__ Vtg, const float* __restrict__ cost,
                 const float* __restrict__ sint, bf16* __restrict__ O, int S) {
  __shared__ bf16 Kl[2][64 * 128];  // [kv][d], 16B chunks XOR-swizzled by kv&7 (pre-swizzled source)
  __shared__ bf16 Vt[2][128 * 64];  // [d][kv], 16B chunks XOR-swizzled by d&7 (pre-swizzled source)
  __shared__ bf16 Pl[4][16 * 64];   // per-wave P, rows XOR-swizzled by row&7
  const int t = threadIdx.x, wid = t >> 6, lane = t & 63;
  const int lr = lane & 15, lk = lane >> 4;
  const int bh = blockIdx.y;
  const int b = bh >> 4, h = bh & 15;
  const int NQ = S >> 6;
  const int qtA = blockIdx.x, qtB = NQ - 1 - qtA;
  const int ntA = qtA + 1, ntB = qtB + 1, total = ntA + ntB;  // == NQ+1 for all blocks
  const bf16* Kb = Kc + (size_t)bh * S * 128;
  const bf16* Vb = Vtg + (size_t)bh * 128 * S;
  const float scale = 0.08838834764831845f;  // 1/sqrt(128)

  bf16x8 qf[4];
  auto loadQ = [&](int q0) {
    int qrow = q0 + wid * 16 + lr;
    const bf16* qp = qkv + (size_t)(b * 2048 + qrow) * 6144 + h * 128;
    bf16x8 raw[4];
#pragma unroll
    for (int kb = 0; kb < 4; ++kb) raw[kb] = *(const bf16x8*)&qp[kb * 32 + lk * 8];
#pragma unroll
    for (int kb = 0; kb < 4; ++kb) {
      const float* cb = cost + (qrow << 6) + ((kb & 1) << 5) + lk * 8;
      const float* sb = sint + (qrow << 6) + ((kb & 1) << 5) + lk * 8;
#pragma unroll
      for (int j = 0; j < 8; ++j) {
        float qv = (float)raw[kb][j];
        float qo = (float)raw[kb ^ 2][j];
        float rot = (kb < 2) ? -qo : qo;   // d<64 <=> kb<2
        qf[kb][j] = (bf16)(qv * cb[j] + rot * sb[j]);
      }
    }
  };
  auto stage = [&](int buf, int kv0) {
#pragma unroll
    for (int c = 0; c < 4; ++c) {
      int fc = c * 256 + t;
      int kvr = fc >> 4, cc = fc & 15;
      GLD16(Kb + (size_t)(kv0 + kvr) * 128 + (cc ^ (kvr & 7)) * 8, &Kl[buf][fc * 8]);
      int dr = fc >> 3, c2 = fc & 7;
      GLD16(Vb + (size_t)dr * S + kv0 + (c2 ^ (dr & 7)) * 8, &Vt[buf][fc * 8]);
    }
  };

  f32x4 o[8] = {};
  float mrun[4], lrun[4];
#pragma unroll
  for (int r = 0; r < 4; ++r) { mrun[r] = -INFINITY; lrun[r] = 0.f; }

  loadQ(qtA * 64);
  stage(0, 0);
  __syncthreads();  // tile 0 resident
  int cur = 0;
  for (int ti = 0; ti < total; ++ti) {
    if (ti + 1 < total) {
      int tn = ti + 1;
      stage(cur ^ 1, ((tn < ntA) ? tn : tn - ntA) * 64);
    }
    __builtin_amdgcn_sched_barrier(0);
    const bool isA = ti < ntA;
    const int tt = isA ? ti : ti - ntA;
    const int nt = isA ? ntA : ntB;
    const int q0 = (isA ? qtA : qtB) * 64;
    const int kv0 = tt * 64;
    f32x4 sa[4];
    __builtin_amdgcn_s_setprio(1);
#pragma unroll
    for (int n = 0; n < 4; ++n) {
      sa[n] = (f32x4){0.f, 0.f, 0.f, 0.f};
      int kvl = n * 16 + lr;
#pragma unroll
      for (int kb = 0; kb < 4; ++kb) {
        bf16x8 kf = *(const bf16x8*)&Kl[cur][kvl * 128 + (((kb << 2) | lk) ^ (kvl & 7)) * 8];
        sa[n] = __builtin_amdgcn_mfma_f32_16x16x32_bf16(qf[kb], kf, sa[n], 0, 0, 0);
      }
    }
    __builtin_amdgcn_s_setprio(0);
    float p[4][4];
    float tmax[4] = {-INFINITY, -INFINITY, -INFINITY, -INFINITY};
    const bool lastTile = (tt == nt - 1);
#pragma unroll
    for (int n = 0; n < 4; ++n)
#pragma unroll
      for (int r = 0; r < 4; ++r) {
        float s = sa[n][r] * scale;
        if (lastTile) {
          int kvg = kv0 + n * 16 + lr;
          int qg = q0 + wid * 16 + lk * 4 + r;
          if (kvg > qg) s = -INFINITY;
        }
        p[n][r] = s;
        tmax[r] = fmaxf(tmax[r], s);
      }
#pragma unroll
    for (int r = 0; r < 4; ++r)
#pragma unroll
      for (int off = 1; off < 16; off <<= 1)
        tmax[r] = fmaxf(tmax[r], __shfl_xor(tmax[r], off));
    float alpha[4], rsum[4];
#pragma unroll
    for (int r = 0; r < 4; ++r) {
      float mnew = fmaxf(mrun[r], tmax[r]);
      alpha[r] = __expf(mrun[r] - mnew);
      mrun[r] = mnew;
      rsum[r] = 0.f;
#pragma unroll
      for (int n = 0; n < 4; ++n) {
        p[n][r] = __expf(p[n][r] - mnew);
        rsum[r] += p[n][r];
      }
    }
#pragma unroll
    for (int r = 0; r < 4; ++r) {
#pragma unroll
      for (int off = 1; off < 16; off <<= 1)
        rsum[r] += __shfl_xor(rsum[r], off);
      lrun[r] = lrun[r] * alpha[r] + rsum[r];
    }
#pragma unroll
    for (int n8 = 0; n8 < 8; ++n8)
#pragma unroll
      for (int r = 0; r < 4; ++r)
        o[n8][r] *= alpha[r];
#pragma unroll
    for (int n = 0; n < 4; ++n)
#pragma unroll
      for (int r = 0; r < 4; ++r) {
        int row = lk * 4 + r, col = n * 16 + lr;
        Pl[wid][(row * 64 + col) ^ ((row & 7) << 3)] = (bf16)p[n][r];
      }
    __builtin_amdgcn_s_setprio(1);
#pragma unroll
    for (int kb2 = 0; kb2 < 2; ++kb2) {
      bf16x8 pf = *(const bf16x8*)&Pl[wid][(lr * 64 + kb2 * 32 + lk * 8) ^ ((lr & 7) << 3)];
#pragma unroll
      for (int n8 = 0; n8 < 8; ++n8) {
        int dcol = n8 * 16 + lr;
        bf16x8 vf = *(const bf16x8*)&Vt[cur][(dcol * 64 + kb2 * 32 + lk * 8) ^ ((dcol & 7) << 3)];
        o[n8] = __builtin_amdgcn_mfma_f32_16x16x32_bf16(pf, vf, o[n8], 0, 0, 0);
      }
    }
    __builtin_amdgcn_s_setprio(0);
    if (ti == ntA - 1) {
#pragma unroll
      for (int r = 0; r < 4; ++r) {
        float rl = 1.0f / lrun[r];
        int row = qtA * 64 + wid * 16 + lk * 4 + r;
        size_t base = ((size_t)(b * S + row)) * 2048 + h * 128;
#pragma unroll
        for (int n8 = 0; n8 < 8; ++n8)
          O[base + n8 * 16 + lr] = (bf16)(o[n8][r] * rl);
      }
#pragma unroll
      for (int n8 = 0; n8 < 8; ++n8) o[n8] = (f32x4){0.f, 0.f, 0.f, 0.f};
#pragma unroll
      for (int r = 0; r < 4; ++r) { mrun[r] = -INFINITY; lrun[r] = 0.f; }
      loadQ(qtB * 64);
    }
    __syncthreads();
    cur ^= 1;
  }
#pragma unroll
  for (int r = 0; r < 4; ++r) {
    float rl = 1.0f / lrun[r];
    int row = qtB * 64 + wid * 16 + lk * 4 + r;
    size_t base = ((size_t)(b * S + row)) * 2048 + h * 128;
#pragma unroll
    for (int n8 = 0; n8 < 8; ++n8)
      O[base + n8 * 16 + lr] = (bf16)(o[n8][r] * rl);
  }
}

// ---------------- launch ----------------

extern "C" void kernel_launch(void* const* d_in, const int* in_sizes, int n_in,
                              void* d_out, int out_size, void* d_ws, size_t ws_size,
                              hipStream_t stream) {
  const float* x  = (const float*)d_in[0];
  const float* Wq = (const float*)d_in[1];
  const float* bq = (const float*)d_in[2];
  const float* Wk = (const float*)d_in[3];
  const float* bk = (const float*)d_in[4];
  const float* Wv = (const float*)d_in[5];
  const float* bv = (const float*)d_in[6];
  const float* Wo = (const float*)d_in[7];
  const float* bo = (const float*)d_in[8];

  char* ws = (char*)d_ws;
  bf16* xb     = (bf16*)(ws);                  // 16 MB (x bf16; reused as attn_out after GEMM1)
  bf16* wqkv   = (bf16*)(ws + 16777216);       // 24 MB (Wq|Wk|Wv bf16, 6144x2048)
  bf16* wob    = (bf16*)(ws + 41943040);       // 8 MB
  bf16* qkv    = (bf16*)(ws + 50331648);       // 50.3 MB, live until attn done
  bf16* kr     = (bf16*)(ws + 100663296);      // 16 MB (RoPE'd K)
  bf16* vt     = (bf16*)(ws + 117440512);      // 16 MB (V^T)
  float* biasq = (float*)(ws + 134217728);     // 24 KB
  float* cost  = (float*)(ws + 134242304);     // 512 KB
  float* sint  = (float*)(ws + 134766592);     // 512 KB (ws end: 135290880)
  bf16* attn_out = xb;                         // alias: x_bf16 dead after GEMM1

  prep_kernel<<<25112, 256, 0, stream>>>(x, Wq, Wk, Wv, Wo, bq, bk, bv,
                                         xb, wqkv, wob, biasq, cost, sint);
  // qkv = x @ [Wq|Wk|Wv]^T + bias  (4096 x 6144 x 2048): 512 blocks = exactly 2 rounds
  gemm256_kernel<192, true, 5><<<dim3(32, 16), 512, 0, stream>>>(xb, wqkv, biasq, qkv, 4096, 6144, 2048);
  rope_k_kernel<<<4096, 256, 0, stream>>>(qkv, cost, sint, kr);
  transpose_v_kernel<<<dim3(2, 32, 32), 256, 0, stream>>>(qkv, vt);
  attn_kernel<<<dim3(16, 32), 256, 0, stream>>>(qkv, kr, vt, cost, sint, attn_out, 2048);
  // out = attn @ Wo^T + bo  (4096 x 2048 x 2048), fp32 out: 256 blocks = exactly 1 round
  gemm256_kernel<128, false, 4><<<dim3(16, 16), 512, 0, stream>>>(attn_out, wob, bo, (float*)d_out, 4096, 2048, 2048);
}